// Round 20
// baseline (329.116 us; speedup 1.0000x reference)
//
#include <hip/hip_runtime.h>
#include <hip/hip_bf16.h>
#include <stdint.h>

// Problem constants (fixed by setup_inputs)
#define T_   24
#define D_   128
#define H_   96
#define W_   128
#define N_   256
#define KP   49      // 7x7 support points
#define K2   3136    // vol K-dim: 49 k-rows x 64 l-slots (l>=49 zero-padded)
#define H1   384     // MLP hidden
#define OUTC 256     // MLP out
#define MTOT (4 * T_ * N_)   // 24576 rows batched over levels

// padded pyramid geometry (8-px zero border on all sides)
#define PAD  8
#define GSTR 68      // Gs row stride in shorts (136B: hi-groups 8 banks apart)

typedef __attribute__((ext_vector_type(8))) __bf16 bf16x8;
typedef __attribute__((ext_vector_type(4))) float f32x4;

typedef __attribute__((address_space(3))) unsigned int lds_u32;
typedef const __attribute__((address_space(1))) unsigned int g_u32;
#define GLOAD16(g, l) __builtin_amdgcn_global_load_lds((g_u32*)(g), (lds_u32*)(l), 16, 0, 0)

__device__ inline float bf2f(unsigned short u) {
    union { unsigned int i; float f; } v; v.i = ((unsigned int)u) << 16; return v.f;
}
__device__ inline unsigned short f2bf(float f) {
    union { float f; unsigned int i; } v; v.f = f;
    unsigned int i = v.i;
    return (unsigned short)((i + 0x7FFFu + ((i >> 16) & 1u)) >> 16);  // RNE
}
// single-instruction packed f32->bf16 (RNE); no builtin on gfx950 -> inline asm
__device__ inline unsigned int cvtpk(float lo, float hi) {
    unsigned int r;
    asm("v_cvt_pk_bf16_f32 %0, %1, %2" : "=v"(r) : "v"(lo), "v"(hi));
    return r;
}

// ---------------- pad zero: BORDER-ONLY iteration ---------------------------
// Border px per frame: top/bottom bands 2*PAD*PW + side bands Hs*2*PAD.
__global__ __launch_bounds__(256) void k_padzero(uint4* __restrict__ fm,
                                                 int Hs, int Ws) {
    int PW = Ws + 2 * PAD, PH = Hs + 2 * PAD;
    int B1 = 2 * PAD * PW;           // top+bottom band px
    int B2 = Hs * 2 * PAD;           // left+right band px
    int ppf = B1 + B2;               // border px per frame
    size_t total = (size_t)ppf * T_ * 16;
    for (size_t idx = (size_t)blockIdx.x * 256 + threadIdx.x; idx < total;
         idx += (size_t)gridDim.x * 256) {
        int u = (int)(idx & 15);
        size_t p = idx >> 4;
        int t = (int)(p / ppf);
        int q = (int)(p % ppf);
        int y, x;
        if (q < B1) {
            int half = q / (PAD * PW);            // 0 top, 1 bottom
            int r = q - half * (PAD * PW);
            y = half ? (PH - PAD + r / PW) : (r / PW);
            x = r % PW;
        } else {
            int r = q - B1;
            y = PAD + r / (2 * PAD);
            int c = r % (2 * PAD);
            x = c < PAD ? c : (PW - PAD + (c - PAD));
        }
        uint4 z = {0u, 0u, 0u, 0u};
        fm[((size_t)t * PH * PW + (size_t)y * PW + x) * 16 + u] = z;
    }
}

// ---------------- w1 transpose via LDS tile (coalesced both sides) ----------
// w1t layout: [nn][k*64 + l], l>=49 zero. Block = 64 nn x one k (64 l-slots).
__global__ __launch_bounds__(256) void k_w1t(const float* __restrict__ w1,
                                             unsigned short* __restrict__ w1t) {
    __shared__ float tile[64][65];
    int bn = blockIdx.x, k = blockIdx.y;       // 6 x 49
    int tid = threadIdx.x;
    int nl = tid & 63, q = tid >> 6;
#pragma unroll
    for (int i = 0; i < 16; ++i) {
        int l = q * 16 + i;
        float v = (l < KP) ? w1[((size_t)k * KP + l) * H1 + bn * 64 + nl] : 0.f;
        tile[l][nl] = v;
    }
    __syncthreads();
#pragma unroll
    for (int i = 0; i < 16; ++i) {
        int nn = q * 16 + i;
        w1t[(size_t)(bn * 64 + nn) * K2 + k * 64 + nl] = f2bf(tile[nl][nn]);
    }
}
__global__ __launch_bounds__(256) void k_w2t(const float* __restrict__ w2,
                                             unsigned short* __restrict__ w2t) {
    int idx = blockIdx.x * 256 + threadIdx.x;           // OUTC*H1
    if (idx >= OUTC * H1) return;
    int j = idx / H1, k = idx % H1;
    w2t[idx] = f2bf(w2[(size_t)k * OUTC + j]);
}

// ---------------- L2 normalize + transpose -> padded (T,H,W,D) bf16 ----------
#define PW0 (W_ + 2 * PAD)
#define FR0 ((size_t)(H_ + 2 * PAD) * PW0 * D_)
__global__ __launch_bounds__(256) void k_normalize(const float* __restrict__ fmaps,
                                                   unsigned short* __restrict__ fm0i) {
    int bid = blockIdx.x;                 // t*H_ + h
    int t = bid / H_, h = bid % H_;
    int tid = threadIdx.x;
    __shared__ float tile[64 * 129];
    __shared__ float ssumP[64][4];
    __shared__ float rs[64];
    const float* base = fmaps + (size_t)t * D_ * H_ * W_ + (size_t)h * W_;
    unsigned short* orow = fm0i + (size_t)t * FR0 + (size_t)h * (PW0 * D_);
    for (int wt = 0; wt < 2; ++wt) {
        int wl = tid & 63, dg = tid >> 6;
        float ss = 0.f;
        for (int i = 0; i < 32; ++i) {
            int d = dg * 32 + i;
            float v = base[(size_t)d * (H_ * W_) + wt * 64 + wl];
            tile[wl * 129 + d] = v;
            ss += v * v;
        }
        ssumP[wl][dg] = ss;
        __syncthreads();
        if (tid < 64)
            rs[tid] = rsqrtf(fmaxf(ssumP[tid][0] + ssumP[tid][1] + ssumP[tid][2] + ssumP[tid][3], 1e-12f));
        __syncthreads();
        int c = tid & 63, rg = tid >> 6;      // u32 col (2 d's), row group
        for (int i = 0; i < 16; ++i) {
            int wll = rg * 16 + i;
            float r = rs[wll];
            float v0 = tile[wll * 129 + c * 2] * r;
            float v1 = tile[wll * 129 + c * 2 + 1] * r;
            *(unsigned int*)(orow + (size_t)(wt * 64 + wll) * D_ + c * 2) = cvtpk(v0, v1);
        }
        __syncthreads();
    }
}

// ---------------- 2x2 avg pool on padded buffers -----------------------------
__global__ __launch_bounds__(256) void k_pool(const unsigned short* __restrict__ ini,
                                              unsigned short* __restrict__ outi,
                                              int Hs, int Ws) {
    int Ho = Hs >> 1, Wo = Ws >> 1;
    int PWi = Ws + 2 * PAD, PWo = Wo + 2 * PAD;
    size_t FRi = (size_t)(Hs + 2 * PAD) * PWi * D_;
    size_t FRo = (size_t)(Ho + 2 * PAD) * PWo * D_;
    size_t total = (size_t)T_ * Ho * Wo * (D_ / 4);
    size_t idx = (size_t)blockIdx.x * 256 + threadIdx.x;
    if (idx >= total) return;
    int d4 = idx & 31;
    size_t p = idx >> 5;
    int x = (int)(p % Wo); p /= Wo;
    int y = (int)(p % Ho); int t = (int)(p / Ho);
    const unsigned short* b0 = ini + (size_t)t * FRi + ((size_t)(2 * y) * PWi + 2 * x) * D_ + d4 * 4;
    const unsigned short* b1r = b0 + (size_t)PWi * D_;
    float acc[4] = {0.f, 0.f, 0.f, 0.f};
#pragma unroll
    for (int j = 0; j < 2; ++j) {
        const unsigned short* bb = j ? b1r : b0;
#pragma unroll
        for (int i = 0; i < 2; ++i) {
            const unsigned short* q = bb + i * D_;
#pragma unroll
            for (int c = 0; c < 4; ++c) acc[c] += bf2f(q[c]);
        }
    }
    unsigned short* o = outi + (size_t)t * FRo + ((size_t)y * PWo + x) * D_ + d4 * 4;
#pragma unroll
    for (int c = 0; c < 4; ++c) o[c] = f2bf(acc[c] * 0.25f);
}

// ---------------- track-support features, templated on LVL ------------------
template <int LVL>
__global__ __launch_bounds__(256) void k_tf(const unsigned short* __restrict__ fmi,
                                            const float* __restrict__ qcoords,
                                            const int* __restrict__ qframes,
                                            unsigned short* __restrict__ tfg) {
    constexpr int Hs = H_ >> LVL, Ws = W_ >> LVL;
    constexpr int PW = Ws + 2 * PAD;
    constexpr size_t FR = (size_t)(Hs + 2 * PAD) * PW * D_;
    constexpr float inv = 1.0f / (float)(1 << LVL);
    int n = blockIdx.x;
    int wid = threadIdx.x >> 6, lane = threadIdx.x & 63;
    int fidx = qframes[n];
    float qx = qcoords[n * 2 + 0] * inv, qy = qcoords[n * 2 + 1] * inv;
    const unsigned short* fb = fmi + (size_t)fidx * FR;
    unsigned short* orow = tfg + ((size_t)LVL * N_ + n) * (64 * D_);
    for (int k = wid; k < 64; k += 4) {
        float acc0 = 0.f, acc1 = 0.f;
        if (k < KP) {
            float px = qx + (float)(k / 7 - 3);
            float py = qy + (float)(k % 7 - 3);
            float x0f = floorf(px), y0f = floorf(py);
            float tx = px - x0f, ty = py - y0f;
            int x0 = (int)x0f, y0 = (int)y0f;
#pragma unroll
            for (int dy = 0; dy < 2; ++dy)
#pragma unroll
                for (int dx = 0; dx < 2; ++dx) {
                    long xi = x0 + dx, yi = y0 + dy;
                    float w = (dx ? tx : 1.f - tx) * (dy ? ty : 1.f - ty);
                    unsigned int pk = *(const unsigned int*)(fb + (yi * PW + xi) * D_ + lane * 2);
                    acc0 += w * bf2f((unsigned short)(pk & 0xffffu));
                    acc1 += w * bf2f((unsigned short)(pk >> 16));
                }
        }
        *(unsigned int*)(orow + k * D_ + lane * 2) = cvtpk(acc0, acc1);
    }
}

// ---------------- cf + 49x49 correlation, templated on LVL ------------------
// r15/r19-proven structure (Gs bf16 overlays tfs after full __syncthreads,
// GSTR=68 pad, cvtpk). LVL constexpr: all dim math constant-folds.
template <int LVL>
__global__ __launch_bounds__(256) void k_cfvol(const unsigned short* __restrict__ fmi,
                                               const float* __restrict__ coords,
                                               const unsigned short* __restrict__ tfg,
                                               unsigned short* __restrict__ vol) {
    constexpr int Hs = H_ >> LVL, Ws = W_ >> LVL;
    constexpr int PW = Ws + 2 * PAD;
    constexpr size_t FR = (size_t)(Hs + 2 * PAD) * PW * D_;
    constexpr float inv = 1.0f / (float)(1 << LVL);
    __shared__ unsigned char tfs[16384];     // tf staging; reused as Gs after barrier
    __shared__ unsigned char Ps[16384];
    unsigned short* Gs = (unsigned short*)tfs;   // bf16 64 x GSTR
    int n = blockIdx.x, t = blockIdx.y;
    int tid = threadIdx.x, wid = tid >> 6, lane = tid & 63;
    int l15 = lane & 15, hi = lane >> 4;

    float cx = coords[((size_t)t * N_ + n) * 2 + 0] * inv;
    float cy = coords[((size_t)t * N_ + n) * 2 + 1] * inv;
    float fx = floorf(cx), fy = floorf(cy);
    float tx = cx - fx, ty = cy - fy;
    long bx = (long)(int)fx - 3, by = (long)(int)fy - 3;
    const unsigned short* fb = fmi + (size_t)t * FR;
    const unsigned short* tfn = tfg + ((size_t)LVL * N_ + n) * (64 * D_);
    // stage tf (16 gload16, 4/wave); LDS linear, source pre-swizzled
#pragma unroll
    for (int i = 0; i < 4; ++i) {
        int rr = wid * 16 + i * 4 + hi;
        int u = l15 ^ (rr & 7);
        GLOAD16(tfn + rr * 128 + u * 8, tfs + (wid * 4 + i) * 1024);
    }
    // stage P: row rr -> pixel (a = rr>>3, b = rr&7)
#pragma unroll
    for (int i = 0; i < 4; ++i) {
        int rr = wid * 16 + i * 4 + hi;
        int u = l15 ^ (rr & 7);
        GLOAD16(fb + ((by + (rr & 7)) * (long)PW + (bx + (rr >> 3))) * D_ + u * 8,
                Ps + (wid * 4 + i) * 1024);
    }
    asm volatile("s_waitcnt vmcnt(0)" ::: "memory");
    __builtin_amdgcn_s_barrier();
    // G = P . tf^T : wave wid computes G rows [wid*16, wid*16+16)
    f32x4 acc[4] = {f32x4{0,0,0,0}, f32x4{0,0,0,0}, f32x4{0,0,0,0}, f32x4{0,0,0,0}};
#pragma unroll
    for (int ks = 0; ks < 4; ++ks) {
        int colb = ks * 64 + hi * 16;
        int arow = wid * 16 + l15;
        bf16x8 a = *(const bf16x8*)(Ps + arow * 256 + (colb ^ ((arow & 7) << 4)));
#pragma unroll
        for (int ln = 0; ln < 4; ++ln) {
            int brow = ln * 16 + l15;
            bf16x8 b = *(const bf16x8*)(tfs + brow * 256 + (colb ^ ((brow & 7) << 4)));
            acc[ln] = __builtin_amdgcn_mfma_f32_16x16x32_bf16(a, b, acc[ln], 0, 0, 0);
        }
    }
    __syncthreads();   // ALL waves' tfs reads complete before overlay writes
#pragma unroll
    for (int ln = 0; ln < 4; ++ln)
#pragma unroll
        for (int r = 0; r < 4; ++r)
            Gs[(wid * 16 + hi * 4 + r) * GSTR + ln * 16 + l15] =
                (unsigned short)cvtpk(acc[ln][r], acc[ln][r]);
    __syncthreads();
    // combine: vol[k*64+l] = w00*G[g,l]+w01*G[g+1,l]+w10*G[g+8,l]+w11*G[g+9,l]
    unsigned int* vrow = (unsigned int*)(vol + (((size_t)LVL * T_ + t) * N_ + n) * K2);
    float w00 = (1.f - tx) * (1.f - ty), w01 = (1.f - tx) * ty;
    float w10 = tx * (1.f - ty), w11 = tx * ty;
    int lh = lane >> 5, ll = lane & 31;
#pragma unroll
    for (int it = 0; it < 7; ++it) {
        int k = it * 8 + wid * 2 + lh;
        if (k < KP) {
            int a0 = k / 7, b0 = k - a0 * 7;
            int g = a0 * 8 + b0;
            const unsigned short* gp = &Gs[g * GSTR + ll * 2];
            unsigned int u00 = *(const unsigned int*)(gp);
            unsigned int u01 = *(const unsigned int*)(gp + GSTR);
            unsigned int u10 = *(const unsigned int*)(gp + 8 * GSTR);
            unsigned int u11 = *(const unsigned int*)(gp + 9 * GSTR);
            float r0 = w00 * bf2f((unsigned short)u00) + w01 * bf2f((unsigned short)u01)
                     + w10 * bf2f((unsigned short)u10) + w11 * bf2f((unsigned short)u11);
            float r1 = w00 * bf2f((unsigned short)(u00 >> 16)) + w01 * bf2f((unsigned short)(u01 >> 16))
                     + w10 * bf2f((unsigned short)(u10 >> 16)) + w11 * bf2f((unsigned short)(u11 >> 16));
            vrow[k * 32 + ll] = cvtpk(r0, r1);
        }
    }
}

// ---------------- GEMM1: (24576 x K2) @ w1t^T (384 x K2), BM=96 BN=128 -------
// Grid 768 = exactly 3 waves of 256 CUs (zero tail). 384 thr (6 waves, 3x2),
// single-buffer {stage, syncthreads, MFMA, syncthreads}, 128B-row XOR swizzle,
// XCD swizzle bn-fastest. (r19-proven)
__global__ __launch_bounds__(384) void k_gemm1(const unsigned short* __restrict__ A,
                                               const unsigned short* __restrict__ Bt,
                                               const float* __restrict__ b1,
                                               unsigned short* __restrict__ Hout) {
    __shared__ unsigned char As[12288];   // 96 rows x 128B, swizzled content
    __shared__ unsigned char Bs[16384];   // 128 rows x 128B
    int bid = blockIdx.x;                           // nwg = 768 = 8 * 96
    int swz = (bid & 7) * 96 + (bid >> 3);
    int bm = swz / 3, bn = swz % 3;
    int tid = threadIdx.x, lane = tid & 63;
    int wid = tid >> 6;                   // 0..5
    int wm = wid >> 1, wn = wid & 1;      // 3 x 2 wave grid
    int l15 = lane & 15, hi = lane >> 4;
    f32x4 acc[2][4] = {};
    const unsigned short* Abase = A + (size_t)(bm * 96) * K2;
    const unsigned short* Bbase = Bt + (size_t)(bn * 128) * K2;
    for (int kt = 0; kt < K2 / 64; ++kt) {        // 49
#pragma unroll
        for (int q = 0; q < 2; ++q) {             // A: 96 rows x 8 units = 768
            int e = q * 384 + tid;
            int row = e >> 3, su = (e & 7) ^ (row & 7);
            GLOAD16(Abase + (size_t)row * K2 + kt * 64 + su * 8,
                    As + q * 6144 + wid * 1024);
        }
#pragma unroll
        for (int q = 0; q < 3; ++q) {             // B: 128 rows x 8 units = 1024
            if (q < 2 || tid < 256) {             // q=2 covers e in [768,1024)
                int e = q * 384 + tid;
                int row = e >> 3, su = (e & 7) ^ (row & 7);
                GLOAD16(Bbase + (size_t)row * K2 + kt * 64 + su * 8,
                        Bs + q * 6144 + wid * 1024);
            }
        }
        __syncthreads();
#pragma unroll
        for (int ks = 0; ks < 2; ++ks) {
            int colb = ks * 64 + hi * 16;
            bf16x8 a[2], b[4];
#pragma unroll
            for (int km = 0; km < 2; ++km) {
                int arow = wm * 32 + km * 16 + l15;
                a[km] = *(const bf16x8*)(As + arow * 128 + (colb ^ ((arow & 7) << 4)));
            }
#pragma unroll
            for (int ln = 0; ln < 4; ++ln) {
                int brow = wn * 64 + ln * 16 + l15;
                b[ln] = *(const bf16x8*)(Bs + brow * 128 + (colb ^ ((brow & 7) << 4)));
            }
#pragma unroll
            for (int km = 0; km < 2; ++km)
#pragma unroll
                for (int ln = 0; ln < 4; ++ln)
                    acc[km][ln] = __builtin_amdgcn_mfma_f32_16x16x32_bf16(a[km], b[ln], acc[km][ln], 0, 0, 0);
        }
        __syncthreads();
    }
#pragma unroll
    for (int km = 0; km < 2; ++km)
#pragma unroll
        for (int ln = 0; ln < 4; ++ln)
#pragma unroll
            for (int r = 0; r < 4; ++r) {
                int row = bm * 96 + wm * 32 + km * 16 + hi * 4 + r;
                int col = bn * 128 + wn * 64 + ln * 16 + l15;
                float x = acc[km][ln][r] + b1[col];
                float g = 0.5f * x * (1.f + erff(x * 0.70710678118654752f));
                Hout[(size_t)row * H1 + col] = f2bf(g);
            }
}

// ---------------- GEMM2: (24576 x 384) @ w2t^T (256 x 384), BM=96 BN=128 -----
// Grid 512 = exactly 2 waves of 256 CUs.
__global__ __launch_bounds__(384) void k_gemm2(const unsigned short* __restrict__ A,
                                               const unsigned short* __restrict__ Bt,
                                               const float* __restrict__ b2,
                                               float* __restrict__ outp) {
    __shared__ unsigned char As[12288];   // 96 x 128B
    __shared__ unsigned char Bs[16384];   // 128 x 128B
    int bid = blockIdx.x;                           // nwg = 512 = 8 * 64
    int swz = (bid & 7) * 64 + (bid >> 3);
    int bm = swz >> 1, bn = swz & 1;
    int tid = threadIdx.x, lane = tid & 63;
    int wid = tid >> 6;
    int wm = wid >> 1, wn = wid & 1;      // 3 x 2
    int l15 = lane & 15, hi = lane >> 4;
    f32x4 acc[2][4] = {};
    const unsigned short* Abase = A + (size_t)(bm * 96) * H1;
    const unsigned short* Bbase = Bt + (size_t)(bn * 128) * H1;
    for (int kt = 0; kt < H1 / 64; ++kt) {        // 6
#pragma unroll
        for (int q = 0; q < 2; ++q) {             // A: 96 x 8 units = 768
            int e = q * 384 + tid;
            int row = e >> 3, su = (e & 7) ^ (row & 7);
            GLOAD16(Abase + (size_t)row * H1 + kt * 64 + su * 8,
                    As + q * 6144 + wid * 1024);
        }
#pragma unroll
        for (int q = 0; q < 3; ++q) {             // B: 128 x 8 units = 1024
            if (q < 2 || tid < 256) {
                int e = q * 384 + tid;
                int row = e >> 3, su = (e & 7) ^ (row & 7);
                GLOAD16(Bbase + (size_t)row * H1 + kt * 64 + su * 8,
                        Bs + q * 6144 + wid * 1024);
            }
        }
        __syncthreads();
#pragma unroll
        for (int ks = 0; ks < 2; ++ks) {
            int colb = ks * 64 + hi * 16;
            bf16x8 a[2], b[4];
#pragma unroll
            for (int km = 0; km < 2; ++km) {
                int arow = wm * 32 + km * 16 + l15;
                a[km] = *(const bf16x8*)(As + arow * 128 + (colb ^ ((arow & 7) << 4)));
            }
#pragma unroll
            for (int ln = 0; ln < 4; ++ln) {
                int brow = wn * 64 + ln * 16 + l15;
                b[ln] = *(const bf16x8*)(Bs + brow * 128 + (colb ^ ((brow & 7) << 4)));
            }
#pragma unroll
            for (int km = 0; km < 2; ++km)
#pragma unroll
                for (int ln = 0; ln < 4; ++ln)
                    acc[km][ln] = __builtin_amdgcn_mfma_f32_16x16x32_bf16(a[km], b[ln], acc[km][ln], 0, 0, 0);
        }
        __syncthreads();
    }
#pragma unroll
    for (int km = 0; km < 2; ++km)
#pragma unroll
        for (int ln = 0; ln < 4; ++ln)
#pragma unroll
            for (int r = 0; r < 4; ++r) {
                int row = bm * 96 + wm * 32 + km * 16 + hi * 4 + r;
                int col = bn * 128 + wn * 64 + ln * 16 + l15;
                int lvl = row / (T_ * N_);
                int r2 = row - lvl * (T_ * N_);
                outp[(size_t)r2 * (4 * OUTC) + lvl * OUTC + col] = acc[km][ln][r] + b2[col];
            }
}

extern "C" void kernel_launch(void* const* d_in, const int* in_sizes, int n_in,
                              void* d_out, int out_size, void* d_ws, size_t ws_size,
                              hipStream_t stream) {
    const float* fmaps   = (const float*)d_in[0];
    const float* coords  = (const float*)d_in[1];
    const float* qcoords = (const float*)d_in[2];
    const int*   qframes = (const int*)d_in[3];
    const float* w1      = (const float*)d_in[4];
    const float* b1      = (const float*)d_in[5];
    const float* w2      = (const float*)d_in[6];
    const float* b2      = (const float*)d_in[7];
    float* outp = (float*)d_out;

    unsigned char* ws = (unsigned char*)d_ws;
    size_t off = 0;
    auto take = [&](size_t bytes) {
        unsigned char* p = ws + off;
        off += (bytes + 255) & ~(size_t)255;
        return p;
    };
    // padded pyramid buffers
    const int Hs[4] = {96, 48, 24, 12}, Wss[4] = {128, 64, 32, 16};
    unsigned short* fmraw[4];
    unsigned short* fmint[4];
    for (int l = 0; l < 4; ++l) {
        int PH = Hs[l] + 2 * PAD, PW = Wss[l] + 2 * PAD;
        fmraw[l] = (unsigned short*)take((size_t)T_ * PH * PW * D_ * 2);
        fmint[l] = fmraw[l] + ((size_t)PAD * PW + PAD) * D_;
    }
    unsigned short* tfg  = (unsigned short*)take((size_t)4 * N_ * 64 * D_ * 2);
    unsigned short* vol  = (unsigned short*)take((size_t)MTOT * K2 * 2);
    unsigned short* hbuf = (unsigned short*)take((size_t)MTOT * H1 * 2);
    unsigned short* w1t  = (unsigned short*)take((size_t)H1 * K2 * 2);
    unsigned short* w2t  = (unsigned short*)take((size_t)OUTC * H1 * 2);

    for (int l = 0; l < 4; ++l)
        hipLaunchKernelGGL(k_padzero, dim3(1024), dim3(256), 0, stream,
                           (uint4*)fmraw[l], Hs[l], Wss[l]);
    hipLaunchKernelGGL(k_w1t, dim3(6, 49), dim3(256), 0, stream, w1, w1t);
    hipLaunchKernelGGL(k_w2t, dim3((OUTC * H1 + 255) / 256), dim3(256), 0, stream, w2, w2t);
    hipLaunchKernelGGL(k_normalize, dim3(T_ * H_), dim3(256), 0, stream, fmaps, fmint[0]);
    hipLaunchKernelGGL(k_pool, dim3((T_ * 48 * 64 * 32 + 255) / 256), dim3(256), 0, stream,
                       fmint[0], fmint[1], 96, 128);
    hipLaunchKernelGGL(k_pool, dim3((T_ * 24 * 32 * 32 + 255) / 256), dim3(256), 0, stream,
                       fmint[1], fmint[2], 48, 64);
    hipLaunchKernelGGL(k_pool, dim3((T_ * 12 * 16 * 32 + 255) / 256), dim3(256), 0, stream,
                       fmint[2], fmint[3], 24, 32);

    hipLaunchKernelGGL(k_tf<0>, dim3(N_), dim3(256), 0, stream, fmint[0], qcoords, qframes, tfg);
    hipLaunchKernelGGL(k_tf<1>, dim3(N_), dim3(256), 0, stream, fmint[1], qcoords, qframes, tfg);
    hipLaunchKernelGGL(k_tf<2>, dim3(N_), dim3(256), 0, stream, fmint[2], qcoords, qframes, tfg);
    hipLaunchKernelGGL(k_tf<3>, dim3(N_), dim3(256), 0, stream, fmint[3], qcoords, qframes, tfg);
    hipLaunchKernelGGL(k_cfvol<0>, dim3(N_, T_), dim3(256), 0, stream, fmint[0], coords, tfg, vol);
    hipLaunchKernelGGL(k_cfvol<1>, dim3(N_, T_), dim3(256), 0, stream, fmint[1], coords, tfg, vol);
    hipLaunchKernelGGL(k_cfvol<2>, dim3(N_, T_), dim3(256), 0, stream, fmint[2], coords, tfg, vol);
    hipLaunchKernelGGL(k_cfvol<3>, dim3(N_, T_), dim3(256), 0, stream, fmint[3], coords, tfg, vol);
    hipLaunchKernelGGL(k_gemm1, dim3(768), dim3(384), 0, stream, vol, w1t, b1, hbuf);
    hipLaunchKernelGGL(k_gemm2, dim3(512), dim3(384), 0, stream, hbuf, w2t, b2, outp);
}

// Round 21
// 290.748 us; speedup vs baseline: 1.1320x; 1.1320x over previous
//
#include <hip/hip_runtime.h>
#include <hip/hip_bf16.h>
#include <stdint.h>

// Problem constants (fixed by setup_inputs)
#define T_   24
#define D_   128
#define H_   96
#define W_   128
#define N_   256
#define KP   49      // 7x7 support points
#define K2   3136    // vol K-dim: 49 k-rows x 64 l-slots (l>=49 zero-padded)
#define H1   384     // MLP hidden
#define OUTC 256     // MLP out
#define MTOT (4 * T_ * N_)   // 24576 rows batched over levels

// padded pyramid geometry (8-px zero border on all sides)
#define PAD  8
#define GSTR 68      // Gs row stride in shorts (136B: hi-groups 8 banks apart)

typedef __attribute__((ext_vector_type(8))) __bf16 bf16x8;
typedef __attribute__((ext_vector_type(4))) float f32x4;

typedef __attribute__((address_space(3))) unsigned int lds_u32;
typedef const __attribute__((address_space(1))) unsigned int g_u32;
#define GLOAD16(g, l) __builtin_amdgcn_global_load_lds((g_u32*)(g), (lds_u32*)(l), 16, 0, 0)

__device__ inline float bf2f(unsigned short u) {
    union { unsigned int i; float f; } v; v.i = ((unsigned int)u) << 16; return v.f;
}
__device__ inline unsigned short f2bf(float f) {
    union { float f; unsigned int i; } v; v.f = f;
    unsigned int i = v.i;
    return (unsigned short)((i + 0x7FFFu + ((i >> 16) & 1u)) >> 16);  // RNE
}
// single-instruction packed f32->bf16 (RNE); no builtin on gfx950 -> inline asm
__device__ inline unsigned int cvtpk(float lo, float hi) {
    unsigned int r;
    asm("v_cvt_pk_bf16_f32 %0, %1, %2" : "=v"(r) : "v"(lo), "v"(hi));
    return r;
}

// ---------------- pad zero: BORDER-ONLY iteration ---------------------------
__global__ __launch_bounds__(256) void k_padzero(uint4* __restrict__ fm,
                                                 int Hs, int Ws) {
    int PW = Ws + 2 * PAD, PH = Hs + 2 * PAD;
    int B1 = 2 * PAD * PW;           // top+bottom band px
    int B2 = Hs * 2 * PAD;           // left+right band px
    int ppf = B1 + B2;               // border px per frame
    size_t total = (size_t)ppf * T_ * 16;
    for (size_t idx = (size_t)blockIdx.x * 256 + threadIdx.x; idx < total;
         idx += (size_t)gridDim.x * 256) {
        int u = (int)(idx & 15);
        size_t p = idx >> 4;
        int t = (int)(p / ppf);
        int q = (int)(p % ppf);
        int y, x;
        if (q < B1) {
            int half = q / (PAD * PW);            // 0 top, 1 bottom
            int r = q - half * (PAD * PW);
            y = half ? (PH - PAD + r / PW) : (r / PW);
            x = r % PW;
        } else {
            int r = q - B1;
            y = PAD + r / (2 * PAD);
            int c = r % (2 * PAD);
            x = c < PAD ? c : (PW - PAD + (c - PAD));
        }
        uint4 z = {0u, 0u, 0u, 0u};
        fm[((size_t)t * PH * PW + (size_t)y * PW + x) * 16 + u] = z;
    }
}

// ---------------- w1 transpose via LDS tile (coalesced both sides) ----------
__global__ __launch_bounds__(256) void k_w1t(const float* __restrict__ w1,
                                             unsigned short* __restrict__ w1t) {
    __shared__ float tile[64][65];
    int bn = blockIdx.x, k = blockIdx.y;       // 6 x 49
    int tid = threadIdx.x;
    int nl = tid & 63, q = tid >> 6;
#pragma unroll
    for (int i = 0; i < 16; ++i) {
        int l = q * 16 + i;
        float v = (l < KP) ? w1[((size_t)k * KP + l) * H1 + bn * 64 + nl] : 0.f;
        tile[l][nl] = v;
    }
    __syncthreads();
#pragma unroll
    for (int i = 0; i < 16; ++i) {
        int nn = q * 16 + i;
        w1t[(size_t)(bn * 64 + nn) * K2 + k * 64 + nl] = f2bf(tile[nl][nn]);
    }
}
__global__ __launch_bounds__(256) void k_w2t(const float* __restrict__ w2,
                                             unsigned short* __restrict__ w2t) {
    int idx = blockIdx.x * 256 + threadIdx.x;           // OUTC*H1
    if (idx >= OUTC * H1) return;
    int j = idx / H1, k = idx % H1;
    w2t[idx] = f2bf(w2[(size_t)k * OUTC + j]);
}

// ---------------- L2 normalize + transpose -> padded (T,H,W,D) bf16 ----------
#define PW0 (W_ + 2 * PAD)
#define FR0 ((size_t)(H_ + 2 * PAD) * PW0 * D_)
__global__ __launch_bounds__(256) void k_normalize(const float* __restrict__ fmaps,
                                                   unsigned short* __restrict__ fm0i) {
    int bid = blockIdx.x;                 // t*H_ + h
    int t = bid / H_, h = bid % H_;
    int tid = threadIdx.x;
    __shared__ float tile[64 * 129];
    __shared__ float ssumP[64][4];
    __shared__ float rs[64];
    const float* base = fmaps + (size_t)t * D_ * H_ * W_ + (size_t)h * W_;
    unsigned short* orow = fm0i + (size_t)t * FR0 + (size_t)h * (PW0 * D_);
    for (int wt = 0; wt < 2; ++wt) {
        int wl = tid & 63, dg = tid >> 6;
        float ss = 0.f;
        for (int i = 0; i < 32; ++i) {
            int d = dg * 32 + i;
            float v = base[(size_t)d * (H_ * W_) + wt * 64 + wl];
            tile[wl * 129 + d] = v;
            ss += v * v;
        }
        ssumP[wl][dg] = ss;
        __syncthreads();
        if (tid < 64)
            rs[tid] = rsqrtf(fmaxf(ssumP[tid][0] + ssumP[tid][1] + ssumP[tid][2] + ssumP[tid][3], 1e-12f));
        __syncthreads();
        int c = tid & 63, rg = tid >> 6;      // u32 col (2 d's), row group
        for (int i = 0; i < 16; ++i) {
            int wll = rg * 16 + i;
            float r = rs[wll];
            float v0 = tile[wll * 129 + c * 2] * r;
            float v1 = tile[wll * 129 + c * 2 + 1] * r;
            *(unsigned int*)(orow + (size_t)(wt * 64 + wll) * D_ + c * 2) = cvtpk(v0, v1);
        }
        __syncthreads();
    }
}

// ---------------- 2x2 avg pool on padded buffers -----------------------------
__global__ __launch_bounds__(256) void k_pool(const unsigned short* __restrict__ ini,
                                              unsigned short* __restrict__ outi,
                                              int Hs, int Ws) {
    int Ho = Hs >> 1, Wo = Ws >> 1;
    int PWi = Ws + 2 * PAD, PWo = Wo + 2 * PAD;
    size_t FRi = (size_t)(Hs + 2 * PAD) * PWi * D_;
    size_t FRo = (size_t)(Ho + 2 * PAD) * PWo * D_;
    size_t total = (size_t)T_ * Ho * Wo * (D_ / 4);
    size_t idx = (size_t)blockIdx.x * 256 + threadIdx.x;
    if (idx >= total) return;
    int d4 = idx & 31;
    size_t p = idx >> 5;
    int x = (int)(p % Wo); p /= Wo;
    int y = (int)(p % Ho); int t = (int)(p / Ho);
    const unsigned short* b0 = ini + (size_t)t * FRi + ((size_t)(2 * y) * PWi + 2 * x) * D_ + d4 * 4;
    const unsigned short* b1r = b0 + (size_t)PWi * D_;
    float acc[4] = {0.f, 0.f, 0.f, 0.f};
#pragma unroll
    for (int j = 0; j < 2; ++j) {
        const unsigned short* bb = j ? b1r : b0;
#pragma unroll
        for (int i = 0; i < 2; ++i) {
            const unsigned short* q = bb + i * D_;
#pragma unroll
            for (int c = 0; c < 4; ++c) acc[c] += bf2f(q[c]);
        }
    }
    unsigned short* o = outi + (size_t)t * FRo + ((size_t)y * PWo + x) * D_ + d4 * 4;
#pragma unroll
    for (int c = 0; c < 4; ++c) o[c] = f2bf(acc[c] * 0.25f);
}

// ---------------- track-support features: templated impl, single launch -----
template <int LVL>
__device__ __forceinline__ void tf_impl(const unsigned short* __restrict__ fmi,
                                        const float* __restrict__ qcoords,
                                        const int* __restrict__ qframes,
                                        unsigned short* __restrict__ tfg) {
    constexpr int Hs = H_ >> LVL, Ws = W_ >> LVL;
    constexpr int PW = Ws + 2 * PAD;
    constexpr size_t FR = (size_t)(Hs + 2 * PAD) * PW * D_;
    constexpr float inv = 1.0f / (float)(1 << LVL);
    int n = blockIdx.x;
    int wid = threadIdx.x >> 6, lane = threadIdx.x & 63;
    int fidx = qframes[n];
    float qx = qcoords[n * 2 + 0] * inv, qy = qcoords[n * 2 + 1] * inv;
    const unsigned short* fb = fmi + (size_t)fidx * FR;
    unsigned short* orow = tfg + ((size_t)LVL * N_ + n) * (64 * D_);
    for (int k = wid; k < 64; k += 4) {
        float acc0 = 0.f, acc1 = 0.f;
        if (k < KP) {
            float px = qx + (float)(k / 7 - 3);
            float py = qy + (float)(k % 7 - 3);
            float x0f = floorf(px), y0f = floorf(py);
            float tx = px - x0f, ty = py - y0f;
            int x0 = (int)x0f, y0 = (int)y0f;
#pragma unroll
            for (int dy = 0; dy < 2; ++dy)
#pragma unroll
                for (int dx = 0; dx < 2; ++dx) {
                    long xi = x0 + dx, yi = y0 + dy;
                    float w = (dx ? tx : 1.f - tx) * (dy ? ty : 1.f - ty);
                    unsigned int pk = *(const unsigned int*)(fb + (yi * PW + xi) * D_ + lane * 2);
                    acc0 += w * bf2f((unsigned short)(pk & 0xffffu));
                    acc1 += w * bf2f((unsigned short)(pk >> 16));
                }
        }
        *(unsigned int*)(orow + k * D_ + lane * 2) = cvtpk(acc0, acc1);
    }
}

__global__ __launch_bounds__(256) void k_tf(const unsigned short* __restrict__ f0,
                                            const unsigned short* __restrict__ f1,
                                            const unsigned short* __restrict__ f2,
                                            const unsigned short* __restrict__ f3,
                                            const float* __restrict__ qcoords,
                                            const int* __restrict__ qframes,
                                            unsigned short* __restrict__ tfg) {
    switch (blockIdx.y) {      // block-uniform branch; dims const-fold per case
        case 0: tf_impl<0>(f0, qcoords, qframes, tfg); break;
        case 1: tf_impl<1>(f1, qcoords, qframes, tfg); break;
        case 2: tf_impl<2>(f2, qcoords, qframes, tfg); break;
        default: tf_impl<3>(f3, qcoords, qframes, tfg); break;
    }
}

// ---------------- cf + 49x49 correlation: templated impl, single launch -----
// r15/r19-proven structure (Gs bf16 overlays tfs after full __syncthreads,
// GSTR=68 pad, cvtpk). LVL constexpr folds all dim math.
template <int LVL>
__device__ __forceinline__ void cfvol_impl(const unsigned short* __restrict__ fmi,
                                           const float* __restrict__ coords,
                                           const unsigned short* __restrict__ tfg,
                                           unsigned short* __restrict__ vol,
                                           unsigned char* tfs, unsigned char* Ps) {
    constexpr int Hs = H_ >> LVL, Ws = W_ >> LVL;
    constexpr int PW = Ws + 2 * PAD;
    constexpr size_t FR = (size_t)(Hs + 2 * PAD) * PW * D_;
    constexpr float inv = 1.0f / (float)(1 << LVL);
    unsigned short* Gs = (unsigned short*)tfs;   // bf16 64 x GSTR overlay
    int n = blockIdx.x, t = blockIdx.y;
    int tid = threadIdx.x, wid = tid >> 6, lane = tid & 63;
    int l15 = lane & 15, hi = lane >> 4;

    float cx = coords[((size_t)t * N_ + n) * 2 + 0] * inv;
    float cy = coords[((size_t)t * N_ + n) * 2 + 1] * inv;
    float fx = floorf(cx), fy = floorf(cy);
    float tx = cx - fx, ty = cy - fy;
    long bx = (long)(int)fx - 3, by = (long)(int)fy - 3;
    const unsigned short* fb = fmi + (size_t)t * FR;
    const unsigned short* tfn = tfg + ((size_t)LVL * N_ + n) * (64 * D_);
    // stage tf (16 gload16, 4/wave); LDS linear, source pre-swizzled
#pragma unroll
    for (int i = 0; i < 4; ++i) {
        int rr = wid * 16 + i * 4 + hi;
        int u = l15 ^ (rr & 7);
        GLOAD16(tfn + rr * 128 + u * 8, tfs + (wid * 4 + i) * 1024);
    }
    // stage P: row rr -> pixel (a = rr>>3, b = rr&7)
#pragma unroll
    for (int i = 0; i < 4; ++i) {
        int rr = wid * 16 + i * 4 + hi;
        int u = l15 ^ (rr & 7);
        GLOAD16(fb + ((by + (rr & 7)) * (long)PW + (bx + (rr >> 3))) * D_ + u * 8,
                Ps + (wid * 4 + i) * 1024);
    }
    asm volatile("s_waitcnt vmcnt(0)" ::: "memory");
    __builtin_amdgcn_s_barrier();
    // G = P . tf^T : wave wid computes G rows [wid*16, wid*16+16)
    f32x4 acc[4] = {f32x4{0,0,0,0}, f32x4{0,0,0,0}, f32x4{0,0,0,0}, f32x4{0,0,0,0}};
#pragma unroll
    for (int ks = 0; ks < 4; ++ks) {
        int colb = ks * 64 + hi * 16;
        int arow = wid * 16 + l15;
        bf16x8 a = *(const bf16x8*)(Ps + arow * 256 + (colb ^ ((arow & 7) << 4)));
#pragma unroll
        for (int ln = 0; ln < 4; ++ln) {
            int brow = ln * 16 + l15;
            bf16x8 b = *(const bf16x8*)(tfs + brow * 256 + (colb ^ ((brow & 7) << 4)));
            acc[ln] = __builtin_amdgcn_mfma_f32_16x16x32_bf16(a, b, acc[ln], 0, 0, 0);
        }
    }
    __syncthreads();   // ALL waves' tfs reads complete before overlay writes
#pragma unroll
    for (int ln = 0; ln < 4; ++ln)
#pragma unroll
        for (int r = 0; r < 4; ++r)
            Gs[(wid * 16 + hi * 4 + r) * GSTR + ln * 16 + l15] =
                (unsigned short)cvtpk(acc[ln][r], acc[ln][r]);
    __syncthreads();
    // combine: vol[k*64+l] = w00*G[g,l]+w01*G[g+1,l]+w10*G[g+8,l]+w11*G[g+9,l]
    unsigned int* vrow = (unsigned int*)(vol + (((size_t)LVL * T_ + t) * N_ + n) * K2);
    float w00 = (1.f - tx) * (1.f - ty), w01 = (1.f - tx) * ty;
    float w10 = tx * (1.f - ty), w11 = tx * ty;
    int lh = lane >> 5, ll = lane & 31;
#pragma unroll
    for (int it = 0; it < 7; ++it) {
        int k = it * 8 + wid * 2 + lh;
        if (k < KP) {
            int a0 = k / 7, b0 = k - a0 * 7;
            int g = a0 * 8 + b0;
            const unsigned short* gp = &Gs[g * GSTR + ll * 2];
            unsigned int u00 = *(const unsigned int*)(gp);
            unsigned int u01 = *(const unsigned int*)(gp + GSTR);
            unsigned int u10 = *(const unsigned int*)(gp + 8 * GSTR);
            unsigned int u11 = *(const unsigned int*)(gp + 9 * GSTR);
            float r0 = w00 * bf2f((unsigned short)u00) + w01 * bf2f((unsigned short)u01)
                     + w10 * bf2f((unsigned short)u10) + w11 * bf2f((unsigned short)u11);
            float r1 = w00 * bf2f((unsigned short)(u00 >> 16)) + w01 * bf2f((unsigned short)(u01 >> 16))
                     + w10 * bf2f((unsigned short)(u10 >> 16)) + w11 * bf2f((unsigned short)(u11 >> 16));
            vrow[k * 32 + ll] = cvtpk(r0, r1);
        }
    }
}

__global__ __launch_bounds__(256) void k_cfvol(const unsigned short* __restrict__ f0,
                                               const unsigned short* __restrict__ f1,
                                               const unsigned short* __restrict__ f2,
                                               const unsigned short* __restrict__ f3,
                                               const float* __restrict__ coords,
                                               const unsigned short* __restrict__ tfg,
                                               unsigned short* __restrict__ vol) {
    __shared__ unsigned char tfs[16384];
    __shared__ unsigned char Ps[16384];
    switch (blockIdx.z) {      // block-uniform; dims const-fold per case
        case 0: cfvol_impl<0>(f0, coords, tfg, vol, tfs, Ps); break;
        case 1: cfvol_impl<1>(f1, coords, tfg, vol, tfs, Ps); break;
        case 2: cfvol_impl<2>(f2, coords, tfg, vol, tfs, Ps); break;
        default: cfvol_impl<3>(f3, coords, tfg, vol, tfs, Ps); break;
    }
}

// ---------------- GEMM1: (24576 x K2) @ w1t^T (384 x K2), BM=96 BN=128 -------
// Grid 768 = exactly 3 waves of 256 CUs (zero tail). 384 thr (6 waves, 3x2),
// single-buffer {stage, syncthreads, MFMA, syncthreads}, 128B-row XOR swizzle,
// XCD swizzle bn-fastest. (r19-proven)
__global__ __launch_bounds__(384) void k_gemm1(const unsigned short* __restrict__ A,
                                               const unsigned short* __restrict__ Bt,
                                               const float* __restrict__ b1,
                                               unsigned short* __restrict__ Hout) {
    __shared__ unsigned char As[12288];   // 96 rows x 128B, swizzled content
    __shared__ unsigned char Bs[16384];   // 128 rows x 128B
    int bid = blockIdx.x;                           // nwg = 768 = 8 * 96
    int swz = (bid & 7) * 96 + (bid >> 3);
    int bm = swz / 3, bn = swz % 3;
    int tid = threadIdx.x, lane = tid & 63;
    int wid = tid >> 6;                   // 0..5
    int wm = wid >> 1, wn = wid & 1;      // 3 x 2 wave grid
    int l15 = lane & 15, hi = lane >> 4;
    f32x4 acc[2][4] = {};
    const unsigned short* Abase = A + (size_t)(bm * 96) * K2;
    const unsigned short* Bbase = Bt + (size_t)(bn * 128) * K2;
    for (int kt = 0; kt < K2 / 64; ++kt) {        // 49
#pragma unroll
        for (int q = 0; q < 2; ++q) {             // A: 96 rows x 8 units = 768
            int e = q * 384 + tid;
            int row = e >> 3, su = (e & 7) ^ (row & 7);
            GLOAD16(Abase + (size_t)row * K2 + kt * 64 + su * 8,
                    As + q * 6144 + wid * 1024);
        }
#pragma unroll
        for (int q = 0; q < 3; ++q) {             // B: 128 rows x 8 units = 1024
            if (q < 2 || tid < 256) {             // q=2 covers e in [768,1024)
                int e = q * 384 + tid;
                int row = e >> 3, su = (e & 7) ^ (row & 7);
                GLOAD16(Bbase + (size_t)row * K2 + kt * 64 + su * 8,
                        Bs + q * 6144 + wid * 1024);
            }
        }
        __syncthreads();
#pragma unroll
        for (int ks = 0; ks < 2; ++ks) {
            int colb = ks * 64 + hi * 16;
            bf16x8 a[2], b[4];
#pragma unroll
            for (int km = 0; km < 2; ++km) {
                int arow = wm * 32 + km * 16 + l15;
                a[km] = *(const bf16x8*)(As + arow * 128 + (colb ^ ((arow & 7) << 4)));
            }
#pragma unroll
            for (int ln = 0; ln < 4; ++ln) {
                int brow = wn * 64 + ln * 16 + l15;
                b[ln] = *(const bf16x8*)(Bs + brow * 128 + (colb ^ ((brow & 7) << 4)));
            }
#pragma unroll
            for (int km = 0; km < 2; ++km)
#pragma unroll
                for (int ln = 0; ln < 4; ++ln)
                    acc[km][ln] = __builtin_amdgcn_mfma_f32_16x16x32_bf16(a[km], b[ln], acc[km][ln], 0, 0, 0);
        }
        __syncthreads();
    }
#pragma unroll
    for (int km = 0; km < 2; ++km)
#pragma unroll
        for (int ln = 0; ln < 4; ++ln)
#pragma unroll
            for (int r = 0; r < 4; ++r) {
                int row = bm * 96 + wm * 32 + km * 16 + hi * 4 + r;
                int col = bn * 128 + wn * 64 + ln * 16 + l15;
                float x = acc[km][ln][r] + b1[col];
                float g = 0.5f * x * (1.f + erff(x * 0.70710678118654752f));
                Hout[(size_t)row * H1 + col] = f2bf(g);
            }
}

// ---------------- GEMM2: (24576 x 384) @ w2t^T (256 x 384), BM=96 BN=128 -----
// Grid 512 = exactly 2 waves of 256 CUs.
__global__ __launch_bounds__(384) void k_gemm2(const unsigned short* __restrict__ A,
                                               const unsigned short* __restrict__ Bt,
                                               const float* __restrict__ b2,
                                               float* __restrict__ outp) {
    __shared__ unsigned char As[12288];   // 96 x 128B
    __shared__ unsigned char Bs[16384];   // 128 x 128B
    int bid = blockIdx.x;                           // nwg = 512 = 8 * 64
    int swz = (bid & 7) * 64 + (bid >> 3);
    int bm = swz >> 1, bn = swz & 1;
    int tid = threadIdx.x, lane = tid & 63;
    int wid = tid >> 6;
    int wm = wid >> 1, wn = wid & 1;      // 3 x 2
    int l15 = lane & 15, hi = lane >> 4;
    f32x4 acc[2][4] = {};
    const unsigned short* Abase = A + (size_t)(bm * 96) * H1;
    const unsigned short* Bbase = Bt + (size_t)(bn * 128) * H1;
    for (int kt = 0; kt < H1 / 64; ++kt) {        // 6
#pragma unroll
        for (int q = 0; q < 2; ++q) {             // A: 96 x 8 units = 768
            int e = q * 384 + tid;
            int row = e >> 3, su = (e & 7) ^ (row & 7);
            GLOAD16(Abase + (size_t)row * H1 + kt * 64 + su * 8,
                    As + q * 6144 + wid * 1024);
        }
#pragma unroll
        for (int q = 0; q < 3; ++q) {             // B: 128 x 8 units = 1024
            if (q < 2 || tid < 256) {
                int e = q * 384 + tid;
                int row = e >> 3, su = (e & 7) ^ (row & 7);
                GLOAD16(Bbase + (size_t)row * H1 + kt * 64 + su * 8,
                        Bs + q * 6144 + wid * 1024);
            }
        }
        __syncthreads();
#pragma unroll
        for (int ks = 0; ks < 2; ++ks) {
            int colb = ks * 64 + hi * 16;
            bf16x8 a[2], b[4];
#pragma unroll
            for (int km = 0; km < 2; ++km) {
                int arow = wm * 32 + km * 16 + l15;
                a[km] = *(const bf16x8*)(As + arow * 128 + (colb ^ ((arow & 7) << 4)));
            }
#pragma unroll
            for (int ln = 0; ln < 4; ++ln) {
                int brow = wn * 64 + ln * 16 + l15;
                b[ln] = *(const bf16x8*)(Bs + brow * 128 + (colb ^ ((brow & 7) << 4)));
            }
#pragma unroll
            for (int km = 0; km < 2; ++km)
#pragma unroll
                for (int ln = 0; ln < 4; ++ln)
                    acc[km][ln] = __builtin_amdgcn_mfma_f32_16x16x32_bf16(a[km], b[ln], acc[km][ln], 0, 0, 0);
        }
        __syncthreads();
    }
#pragma unroll
    for (int km = 0; km < 2; ++km)
#pragma unroll
        for (int ln = 0; ln < 4; ++ln)
#pragma unroll
            for (int r = 0; r < 4; ++r) {
                int row = bm * 96 + wm * 32 + km * 16 + hi * 4 + r;
                int col = bn * 128 + wn * 64 + ln * 16 + l15;
                int lvl = row / (T_ * N_);
                int r2 = row - lvl * (T_ * N_);
                outp[(size_t)r2 * (4 * OUTC) + lvl * OUTC + col] = acc[km][ln][r] + b2[col];
            }
}

extern "C" void kernel_launch(void* const* d_in, const int* in_sizes, int n_in,
                              void* d_out, int out_size, void* d_ws, size_t ws_size,
                              hipStream_t stream) {
    const float* fmaps   = (const float*)d_in[0];
    const float* coords  = (const float*)d_in[1];
    const float* qcoords = (const float*)d_in[2];
    const int*   qframes = (const int*)d_in[3];
    const float* w1      = (const float*)d_in[4];
    const float* b1      = (const float*)d_in[5];
    const float* w2      = (const float*)d_in[6];
    const float* b2      = (const float*)d_in[7];
    float* outp = (float*)d_out;

    unsigned char* ws = (unsigned char*)d_ws;
    size_t off = 0;
    auto take = [&](size_t bytes) {
        unsigned char* p = ws + off;
        off += (bytes + 255) & ~(size_t)255;
        return p;
    };
    // padded pyramid buffers
    const int Hs[4] = {96, 48, 24, 12}, Wss[4] = {128, 64, 32, 16};
    unsigned short* fmraw[4];
    unsigned short* fmint[4];
    for (int l = 0; l < 4; ++l) {
        int PH = Hs[l] + 2 * PAD, PW = Wss[l] + 2 * PAD;
        fmraw[l] = (unsigned short*)take((size_t)T_ * PH * PW * D_ * 2);
        fmint[l] = fmraw[l] + ((size_t)PAD * PW + PAD) * D_;
    }
    unsigned short* tfg  = (unsigned short*)take((size_t)4 * N_ * 64 * D_ * 2);
    unsigned short* vol  = (unsigned short*)take((size_t)MTOT * K2 * 2);
    unsigned short* hbuf = (unsigned short*)take((size_t)MTOT * H1 * 2);
    unsigned short* w1t  = (unsigned short*)take((size_t)H1 * K2 * 2);
    unsigned short* w2t  = (unsigned short*)take((size_t)OUTC * H1 * 2);

    for (int l = 0; l < 4; ++l)
        hipLaunchKernelGGL(k_padzero, dim3(1024), dim3(256), 0, stream,
                           (uint4*)fmraw[l], Hs[l], Wss[l]);
    hipLaunchKernelGGL(k_w1t, dim3(6, 49), dim3(256), 0, stream, w1, w1t);
    hipLaunchKernelGGL(k_w2t, dim3((OUTC * H1 + 255) / 256), dim3(256), 0, stream, w2, w2t);
    hipLaunchKernelGGL(k_normalize, dim3(T_ * H_), dim3(256), 0, stream, fmaps, fmint[0]);
    hipLaunchKernelGGL(k_pool, dim3((T_ * 48 * 64 * 32 + 255) / 256), dim3(256), 0, stream,
                       fmint[0], fmint[1], 96, 128);
    hipLaunchKernelGGL(k_pool, dim3((T_ * 24 * 32 * 32 + 255) / 256), dim3(256), 0, stream,
                       fmint[1], fmint[2], 48, 64);
    hipLaunchKernelGGL(k_pool, dim3((T_ * 12 * 16 * 32 + 255) / 256), dim3(256), 0, stream,
                       fmint[2], fmint[3], 24, 32);

    hipLaunchKernelGGL(k_tf, dim3(N_, 4), dim3(256), 0, stream,
                       fmint[0], fmint[1], fmint[2], fmint[3], qcoords, qframes, tfg);
    hipLaunchKernelGGL(k_cfvol, dim3(N_, T_, 4), dim3(256), 0, stream,
                       fmint[0], fmint[1], fmint[2], fmint[3], coords, tfg, vol);
    hipLaunchKernelGGL(k_gemm1, dim3(768), dim3(384), 0, stream, vol, w1t, b1, hbuf);
    hipLaunchKernelGGL(k_gemm2, dim3(512), dim3(384), 0, stream, hbuf, w2t, b2, outp);
}

// Round 23
// 289.278 us; speedup vs baseline: 1.1377x; 1.0051x over previous
//
#include <hip/hip_runtime.h>
#include <hip/hip_bf16.h>
#include <stdint.h>

// Problem constants (fixed by setup_inputs)
#define T_   24
#define D_   128
#define H_   96
#define W_   128
#define N_   256
#define KP   49      // 7x7 support points
#define K2   3136    // vol K-dim: 49 k-rows x 64 l-slots (l>=49 zero-padded)
#define H1   384     // MLP hidden
#define OUTC 256     // MLP out
#define MTOT (4 * T_ * N_)   // 24576 rows batched over levels

// padded pyramid geometry (8-px zero border on all sides)
#define PAD  8
#define GSTR 68      // Gs row stride in shorts (136B: hi-groups 8 banks apart)

typedef __attribute__((ext_vector_type(8))) __bf16 bf16x8;
typedef __attribute__((ext_vector_type(4))) float f32x4;

typedef __attribute__((address_space(3))) unsigned int lds_u32;
typedef const __attribute__((address_space(1))) unsigned int g_u32;
#define GLOAD16(g, l) __builtin_amdgcn_global_load_lds((g_u32*)(g), (lds_u32*)(l), 16, 0, 0)

__device__ inline float bf2f(unsigned short u) {
    union { unsigned int i; float f; } v; v.i = ((unsigned int)u) << 16; return v.f;
}
__device__ inline unsigned short f2bf(float f) {
    union { float f; unsigned int i; } v; v.f = f;
    unsigned int i = v.i;
    return (unsigned short)((i + 0x7FFFu + ((i >> 16) & 1u)) >> 16);  // RNE
}
// single-instruction packed f32->bf16 (RNE); no builtin on gfx950 -> inline asm
__device__ inline unsigned int cvtpk(float lo, float hi) {
    unsigned int r;
    asm("v_cvt_pk_bf16_f32 %0, %1, %2" : "=v"(r) : "v"(lo), "v"(hi));
    return r;
}

// ---------------- pad zero: BORDER-ONLY iteration ---------------------------
__global__ __launch_bounds__(256) void k_padzero(uint4* __restrict__ fm,
                                                 int Hs, int Ws) {
    int PW = Ws + 2 * PAD, PH = Hs + 2 * PAD;
    int B1 = 2 * PAD * PW;           // top+bottom band px
    int B2 = Hs * 2 * PAD;           // left+right band px
    int ppf = B1 + B2;               // border px per frame
    size_t total = (size_t)ppf * T_ * 16;
    for (size_t idx = (size_t)blockIdx.x * 256 + threadIdx.x; idx < total;
         idx += (size_t)gridDim.x * 256) {
        int u = (int)(idx & 15);
        size_t p = idx >> 4;
        int t = (int)(p / ppf);
        int q = (int)(p % ppf);
        int y, x;
        if (q < B1) {
            int half = q / (PAD * PW);            // 0 top, 1 bottom
            int r = q - half * (PAD * PW);
            y = half ? (PH - PAD + r / PW) : (r / PW);
            x = r % PW;
        } else {
            int r = q - B1;
            y = PAD + r / (2 * PAD);
            int c = r % (2 * PAD);
            x = c < PAD ? c : (PW - PAD + (c - PAD));
        }
        uint4 z = {0u, 0u, 0u, 0u};
        fm[((size_t)t * PH * PW + (size_t)y * PW + x) * 16 + u] = z;
    }
}

// ---------------- w1 transpose via LDS tile (coalesced both sides) ----------
__global__ __launch_bounds__(256) void k_w1t(const float* __restrict__ w1,
                                             unsigned short* __restrict__ w1t) {
    __shared__ float tile[64][65];
    int bn = blockIdx.x, k = blockIdx.y;       // 6 x 49
    int tid = threadIdx.x;
    int nl = tid & 63, q = tid >> 6;
#pragma unroll
    for (int i = 0; i < 16; ++i) {
        int l = q * 16 + i;
        float v = (l < KP) ? w1[((size_t)k * KP + l) * H1 + bn * 64 + nl] : 0.f;
        tile[l][nl] = v;
    }
    __syncthreads();
#pragma unroll
    for (int i = 0; i < 16; ++i) {
        int nn = q * 16 + i;
        w1t[(size_t)(bn * 64 + nn) * K2 + k * 64 + nl] = f2bf(tile[nl][nn]);
    }
}
__global__ __launch_bounds__(256) void k_w2t(const float* __restrict__ w2,
                                             unsigned short* __restrict__ w2t) {
    int idx = blockIdx.x * 256 + threadIdx.x;           // OUTC*H1
    if (idx >= OUTC * H1) return;
    int j = idx / H1, k = idx % H1;
    w2t[idx] = f2bf(w2[(size_t)k * OUTC + j]);
}

// ---------------- L2 normalize + transpose -> padded (T,H,W,D) bf16 ----------
#define PW0 (W_ + 2 * PAD)
#define FR0 ((size_t)(H_ + 2 * PAD) * PW0 * D_)
__global__ __launch_bounds__(256) void k_normalize(const float* __restrict__ fmaps,
                                                   unsigned short* __restrict__ fm0i) {
    int bid = blockIdx.x;                 // t*H_ + h
    int t = bid / H_, h = bid % H_;
    int tid = threadIdx.x;
    __shared__ float tile[64 * 129];
    __shared__ float ssumP[64][4];
    __shared__ float rs[64];
    const float* base = fmaps + (size_t)t * D_ * H_ * W_ + (size_t)h * W_;
    unsigned short* orow = fm0i + (size_t)t * FR0 + (size_t)h * (PW0 * D_);
    for (int wt = 0; wt < 2; ++wt) {
        int wl = tid & 63, dg = tid >> 6;
        float ss = 0.f;
        for (int i = 0; i < 32; ++i) {
            int d = dg * 32 + i;
            float v = base[(size_t)d * (H_ * W_) + wt * 64 + wl];
            tile[wl * 129 + d] = v;
            ss += v * v;
        }
        ssumP[wl][dg] = ss;
        __syncthreads();
        if (tid < 64)
            rs[tid] = rsqrtf(fmaxf(ssumP[tid][0] + ssumP[tid][1] + ssumP[tid][2] + ssumP[tid][3], 1e-12f));
        __syncthreads();
        int c = tid & 63, rg = tid >> 6;      // u32 col (2 d's), row group
        for (int i = 0; i < 16; ++i) {
            int wll = rg * 16 + i;
            float r = rs[wll];
            float v0 = tile[wll * 129 + c * 2] * r;
            float v1 = tile[wll * 129 + c * 2 + 1] * r;
            *(unsigned int*)(orow + (size_t)(wt * 64 + wll) * D_ + c * 2) = cvtpk(v0, v1);
        }
        __syncthreads();
    }
}

// ---------------- 2x2 avg pool on padded buffers -----------------------------
__global__ __launch_bounds__(256) void k_pool(const unsigned short* __restrict__ ini,
                                              unsigned short* __restrict__ outi,
                                              int Hs, int Ws) {
    int Ho = Hs >> 1, Wo = Ws >> 1;
    int PWi = Ws + 2 * PAD, PWo = Wo + 2 * PAD;
    size_t FRi = (size_t)(Hs + 2 * PAD) * PWi * D_;
    size_t FRo = (size_t)(Ho + 2 * PAD) * PWo * D_;
    size_t total = (size_t)T_ * Ho * Wo * (D_ / 4);
    size_t idx = (size_t)blockIdx.x * 256 + threadIdx.x;
    if (idx >= total) return;
    int d4 = idx & 31;
    size_t p = idx >> 5;
    int x = (int)(p % Wo); p /= Wo;
    int y = (int)(p % Ho); int t = (int)(p / Ho);
    const unsigned short* b0 = ini + (size_t)t * FRi + ((size_t)(2 * y) * PWi + 2 * x) * D_ + d4 * 4;
    const unsigned short* b1r = b0 + (size_t)PWi * D_;
    float acc[4] = {0.f, 0.f, 0.f, 0.f};
#pragma unroll
    for (int j = 0; j < 2; ++j) {
        const unsigned short* bb = j ? b1r : b0;
#pragma unroll
        for (int i = 0; i < 2; ++i) {
            const unsigned short* q = bb + i * D_;
#pragma unroll
            for (int c = 0; c < 4; ++c) acc[c] += bf2f(q[c]);
        }
    }
    unsigned short* o = outi + (size_t)t * FRo + ((size_t)y * PWo + x) * D_ + d4 * 4;
#pragma unroll
    for (int c = 0; c < 4; ++c) o[c] = f2bf(acc[c] * 0.25f);
}

// ---------------- track-support features: templated impl, single launch -----
template <int LVL>
__device__ __forceinline__ void tf_impl(const unsigned short* __restrict__ fmi,
                                        const float* __restrict__ qcoords,
                                        const int* __restrict__ qframes,
                                        unsigned short* __restrict__ tfg) {
    constexpr int Hs = H_ >> LVL, Ws = W_ >> LVL;
    constexpr int PW = Ws + 2 * PAD;
    constexpr size_t FR = (size_t)(Hs + 2 * PAD) * PW * D_;
    constexpr float inv = 1.0f / (float)(1 << LVL);
    int n = blockIdx.x;
    int wid = threadIdx.x >> 6, lane = threadIdx.x & 63;
    int fidx = qframes[n];
    float qx = qcoords[n * 2 + 0] * inv, qy = qcoords[n * 2 + 1] * inv;
    const unsigned short* fb = fmi + (size_t)fidx * FR;
    unsigned short* orow = tfg + ((size_t)LVL * N_ + n) * (64 * D_);
    for (int k = wid; k < 64; k += 4) {
        float acc0 = 0.f, acc1 = 0.f;
        if (k < KP) {
            float px = qx + (float)(k / 7 - 3);
            float py = qy + (float)(k % 7 - 3);
            float x0f = floorf(px), y0f = floorf(py);
            float tx = px - x0f, ty = py - y0f;
            int x0 = (int)x0f, y0 = (int)y0f;
#pragma unroll
            for (int dy = 0; dy < 2; ++dy)
#pragma unroll
                for (int dx = 0; dx < 2; ++dx) {
                    long xi = x0 + dx, yi = y0 + dy;
                    float w = (dx ? tx : 1.f - tx) * (dy ? ty : 1.f - ty);
                    unsigned int pk = *(const unsigned int*)(fb + (yi * PW + xi) * D_ + lane * 2);
                    acc0 += w * bf2f((unsigned short)(pk & 0xffffu));
                    acc1 += w * bf2f((unsigned short)(pk >> 16));
                }
        }
        *(unsigned int*)(orow + k * D_ + lane * 2) = cvtpk(acc0, acc1);
    }
}

__global__ __launch_bounds__(256) void k_tf(const unsigned short* __restrict__ f0,
                                            const unsigned short* __restrict__ f1,
                                            const unsigned short* __restrict__ f2,
                                            const unsigned short* __restrict__ f3,
                                            const float* __restrict__ qcoords,
                                            const int* __restrict__ qframes,
                                            unsigned short* __restrict__ tfg) {
    switch (blockIdx.y) {      // block-uniform branch; dims const-fold per case
        case 0: tf_impl<0>(f0, qcoords, qframes, tfg); break;
        case 1: tf_impl<1>(f1, qcoords, qframes, tfg); break;
        case 2: tf_impl<2>(f2, qcoords, qframes, tfg); break;
        default: tf_impl<3>(f3, qcoords, qframes, tfg); break;
    }
}

// ---------------- cf + 49x49 correlation: templated impl, single launch -----
// r15/r19/r21-proven structure; combine loop is the r21-proven SCALAR form
// verbatim (the r22 f32x2 rewrite failed validation — combine-loop rewrites
// are the common factor in every unexplained failure this session; do not
// touch this loop again).
template <int LVL>
__device__ __forceinline__ void cfvol_impl(const unsigned short* __restrict__ fmi,
                                           const float* __restrict__ coords,
                                           const unsigned short* __restrict__ tfg,
                                           unsigned short* __restrict__ vol,
                                           unsigned char* tfs, unsigned char* Ps) {
    constexpr int Hs = H_ >> LVL, Ws = W_ >> LVL;
    constexpr int PW = Ws + 2 * PAD;
    constexpr size_t FR = (size_t)(Hs + 2 * PAD) * PW * D_;
    constexpr float inv = 1.0f / (float)(1 << LVL);
    unsigned short* Gs = (unsigned short*)tfs;   // bf16 64 x GSTR overlay
    int n = blockIdx.x, t = blockIdx.y;
    int tid = threadIdx.x, wid = tid >> 6, lane = tid & 63;
    int l15 = lane & 15, hi = lane >> 4;

    float cx = coords[((size_t)t * N_ + n) * 2 + 0] * inv;
    float cy = coords[((size_t)t * N_ + n) * 2 + 1] * inv;
    float fx = floorf(cx), fy = floorf(cy);
    float tx = cx - fx, ty = cy - fy;
    long bx = (long)(int)fx - 3, by = (long)(int)fy - 3;
    const unsigned short* fb = fmi + (size_t)t * FR;
    const unsigned short* tfn = tfg + ((size_t)LVL * N_ + n) * (64 * D_);
    // stage tf (16 gload16, 4/wave); LDS linear, source pre-swizzled
#pragma unroll
    for (int i = 0; i < 4; ++i) {
        int rr = wid * 16 + i * 4 + hi;
        int u = l15 ^ (rr & 7);
        GLOAD16(tfn + rr * 128 + u * 8, tfs + (wid * 4 + i) * 1024);
    }
    // stage P: row rr -> pixel (a = rr>>3, b = rr&7)
#pragma unroll
    for (int i = 0; i < 4; ++i) {
        int rr = wid * 16 + i * 4 + hi;
        int u = l15 ^ (rr & 7);
        GLOAD16(fb + ((by + (rr & 7)) * (long)PW + (bx + (rr >> 3))) * D_ + u * 8,
                Ps + (wid * 4 + i) * 1024);
    }
    asm volatile("s_waitcnt vmcnt(0)" ::: "memory");
    __builtin_amdgcn_s_barrier();
    // G = P . tf^T : wave wid computes G rows [wid*16, wid*16+16)
    f32x4 acc[4] = {f32x4{0,0,0,0}, f32x4{0,0,0,0}, f32x4{0,0,0,0}, f32x4{0,0,0,0}};
#pragma unroll
    for (int ks = 0; ks < 4; ++ks) {
        int colb = ks * 64 + hi * 16;
        int arow = wid * 16 + l15;
        bf16x8 a = *(const bf16x8*)(Ps + arow * 256 + (colb ^ ((arow & 7) << 4)));
#pragma unroll
        for (int ln = 0; ln < 4; ++ln) {
            int brow = ln * 16 + l15;
            bf16x8 b = *(const bf16x8*)(tfs + brow * 256 + (colb ^ ((brow & 7) << 4)));
            acc[ln] = __builtin_amdgcn_mfma_f32_16x16x32_bf16(a, b, acc[ln], 0, 0, 0);
        }
    }
    __syncthreads();   // ALL waves' tfs reads complete before overlay writes
#pragma unroll
    for (int ln = 0; ln < 4; ++ln)
#pragma unroll
        for (int r = 0; r < 4; ++r)
            Gs[(wid * 16 + hi * 4 + r) * GSTR + ln * 16 + l15] =
                (unsigned short)cvtpk(acc[ln][r], acc[ln][r]);
    __syncthreads();
    // combine: vol[k*64+l] = w00*G[g,l]+w01*G[g+1,l]+w10*G[g+8,l]+w11*G[g+9,l]
    unsigned int* vrow = (unsigned int*)(vol + (((size_t)LVL * T_ + t) * N_ + n) * K2);
    float w00 = (1.f - tx) * (1.f - ty), w01 = (1.f - tx) * ty;
    float w10 = tx * (1.f - ty), w11 = tx * ty;
    int lh = lane >> 5, ll = lane & 31;
#pragma unroll
    for (int it = 0; it < 7; ++it) {
        int k = it * 8 + wid * 2 + lh;
        if (k < KP) {
            int a0 = k / 7, b0 = k - a0 * 7;
            int g = a0 * 8 + b0;
            const unsigned short* gp = &Gs[g * GSTR + ll * 2];
            unsigned int u00 = *(const unsigned int*)(gp);
            unsigned int u01 = *(const unsigned int*)(gp + GSTR);
            unsigned int u10 = *(const unsigned int*)(gp + 8 * GSTR);
            unsigned int u11 = *(const unsigned int*)(gp + 9 * GSTR);
            float r0 = w00 * bf2f((unsigned short)u00) + w01 * bf2f((unsigned short)u01)
                     + w10 * bf2f((unsigned short)u10) + w11 * bf2f((unsigned short)u11);
            float r1 = w00 * bf2f((unsigned short)(u00 >> 16)) + w01 * bf2f((unsigned short)(u01 >> 16))
                     + w10 * bf2f((unsigned short)(u10 >> 16)) + w11 * bf2f((unsigned short)(u11 >> 16));
            vrow[k * 32 + ll] = cvtpk(r0, r1);
        }
    }
}

__global__ __launch_bounds__(256) void k_cfvol(const unsigned short* __restrict__ f0,
                                               const unsigned short* __restrict__ f1,
                                               const unsigned short* __restrict__ f2,
                                               const unsigned short* __restrict__ f3,
                                               const float* __restrict__ coords,
                                               const unsigned short* __restrict__ tfg,
                                               unsigned short* __restrict__ vol) {
    __shared__ unsigned char tfs[16384];
    __shared__ unsigned char Ps[16384];
    switch (blockIdx.z) {      // block-uniform; dims const-fold per case
        case 0: cfvol_impl<0>(f0, coords, tfg, vol, tfs, Ps); break;
        case 1: cfvol_impl<1>(f1, coords, tfg, vol, tfs, Ps); break;
        case 2: cfvol_impl<2>(f2, coords, tfg, vol, tfs, Ps); break;
        default: cfvol_impl<3>(f3, coords, tfg, vol, tfs, Ps); break;
    }
}

// ---------------- GEMM1: (24576 x K2) @ w1t^T (384 x K2), BM=96 BN=192 -------
// Grid 512 = EXACTLY 2 tail-free rounds of 256 CUs (was 768 = 3): per-CU
// serial K-steps 147 -> 98. 384 thr (6 waves 3x2, per-wave 32 rows x 96 cols,
// 24 MFMA/step). Single-buffer {stage, syncthreads, MFMA, syncthreads},
// 128B-row XOR swizzle, XCD swizzle. LDS 36KB.
__global__ __launch_bounds__(384) void k_gemm1(const unsigned short* __restrict__ A,
                                               const unsigned short* __restrict__ Bt,
                                               const float* __restrict__ b1,
                                               unsigned short* __restrict__ Hout) {
    __shared__ unsigned char As[12288];   // 96 rows x 128B, swizzled content
    __shared__ unsigned char Bs[24576];   // 192 rows x 128B
    int bid = blockIdx.x;                           // nwg = 512 = 8 * 64
    int swz = (bid & 7) * 64 + (bid >> 3);
    int bm = swz >> 1, bn = swz & 1;
    int tid = threadIdx.x, lane = tid & 63;
    int wid = tid >> 6;                   // 0..5
    int wm = wid >> 1, wn = wid & 1;      // 3 x 2 wave grid
    int l15 = lane & 15, hi = lane >> 4;
    f32x4 acc[2][6] = {};
    const unsigned short* Abase = A + (size_t)(bm * 96) * K2;
    const unsigned short* Bbase = Bt + (size_t)(bn * 192) * K2;
    for (int kt = 0; kt < K2 / 64; ++kt) {        // 49
#pragma unroll
        for (int q = 0; q < 2; ++q) {             // A: 96 rows x 8 units = 768
            int e = q * 384 + tid;
            int row = e >> 3, su = (e & 7) ^ (row & 7);
            GLOAD16(Abase + (size_t)row * K2 + kt * 64 + su * 8,
                    As + q * 6144 + wid * 1024);
        }
#pragma unroll
        for (int q = 0; q < 4; ++q) {             // B: 192 rows x 8 units = 1536
            int e = q * 384 + tid;
            int row = e >> 3, su = (e & 7) ^ (row & 7);
            GLOAD16(Bbase + (size_t)row * K2 + kt * 64 + su * 8,
                    Bs + q * 6144 + wid * 1024);
        }
        __syncthreads();
#pragma unroll
        for (int ks = 0; ks < 2; ++ks) {
            int colb = ks * 64 + hi * 16;
            bf16x8 a[2], b[6];
#pragma unroll
            for (int km = 0; km < 2; ++km) {
                int arow = wm * 32 + km * 16 + l15;
                a[km] = *(const bf16x8*)(As + arow * 128 + (colb ^ ((arow & 7) << 4)));
            }
#pragma unroll
            for (int ln = 0; ln < 6; ++ln) {
                int brow = wn * 96 + ln * 16 + l15;
                b[ln] = *(const bf16x8*)(Bs + brow * 128 + (colb ^ ((brow & 7) << 4)));
            }
#pragma unroll
            for (int km = 0; km < 2; ++km)
#pragma unroll
                for (int ln = 0; ln < 6; ++ln)
                    acc[km][ln] = __builtin_amdgcn_mfma_f32_16x16x32_bf16(a[km], b[ln], acc[km][ln], 0, 0, 0);
        }
        __syncthreads();
    }
#pragma unroll
    for (int km = 0; km < 2; ++km)
#pragma unroll
        for (int ln = 0; ln < 6; ++ln)
#pragma unroll
            for (int r = 0; r < 4; ++r) {
                int row = bm * 96 + wm * 32 + km * 16 + hi * 4 + r;
                int col = bn * 192 + wn * 96 + ln * 16 + l15;
                float x = acc[km][ln][r] + b1[col];
                float g = 0.5f * x * (1.f + erff(x * 0.70710678118654752f));
                Hout[(size_t)row * H1 + col] = f2bf(g);
            }
}

// ---------------- GEMM2: (24576 x 384) @ w2t^T (256 x 384), BM=96 BN=128 -----
// Grid 512 = exactly 2 waves of 256 CUs. (r19-proven)
__global__ __launch_bounds__(384) void k_gemm2(const unsigned short* __restrict__ A,
                                               const unsigned short* __restrict__ Bt,
                                               const float* __restrict__ b2,
                                               float* __restrict__ outp) {
    __shared__ unsigned char As[12288];   // 96 x 128B
    __shared__ unsigned char Bs[16384];   // 128 x 128B
    int bid = blockIdx.x;                           // nwg = 512 = 8 * 64
    int swz = (bid & 7) * 64 + (bid >> 3);
    int bm = swz >> 1, bn = swz & 1;
    int tid = threadIdx.x, lane = tid & 63;
    int wid = tid >> 6;
    int wm = wid >> 1, wn = wid & 1;      // 3 x 2
    int l15 = lane & 15, hi = lane >> 4;
    f32x4 acc[2][4] = {};
    const unsigned short* Abase = A + (size_t)(bm * 96) * H1;
    const unsigned short* Bbase = Bt + (size_t)(bn * 128) * H1;
    for (int kt = 0; kt < H1 / 64; ++kt) {        // 6
#pragma unroll
        for (int q = 0; q < 2; ++q) {             // A: 96 x 8 units = 768
            int e = q * 384 + tid;
            int row = e >> 3, su = (e & 7) ^ (row & 7);
            GLOAD16(Abase + (size_t)row * H1 + kt * 64 + su * 8,
                    As + q * 6144 + wid * 1024);
        }
#pragma unroll
        for (int q = 0; q < 3; ++q) {             // B: 128 x 8 units = 1024
            if (q < 2 || tid < 256) {
                int e = q * 384 + tid;
                int row = e >> 3, su = (e & 7) ^ (row & 7);
                GLOAD16(Bbase + (size_t)row * H1 + kt * 64 + su * 8,
                        Bs + q * 6144 + wid * 1024);
            }
        }
        __syncthreads();
#pragma unroll
        for (int ks = 0; ks < 2; ++ks) {
            int colb = ks * 64 + hi * 16;
            bf16x8 a[2], b[4];
#pragma unroll
            for (int km = 0; km < 2; ++km) {
                int arow = wm * 32 + km * 16 + l15;
                a[km] = *(const bf16x8*)(As + arow * 128 + (colb ^ ((arow & 7) << 4)));
            }
#pragma unroll
            for (int ln = 0; ln < 4; ++ln) {
                int brow = wn * 64 + ln * 16 + l15;
                b[ln] = *(const bf16x8*)(Bs + brow * 128 + (colb ^ ((brow & 7) << 4)));
            }
#pragma unroll
            for (int km = 0; km < 2; ++km)
#pragma unroll
                for (int ln = 0; ln < 4; ++ln)
                    acc[km][ln] = __builtin_amdgcn_mfma_f32_16x16x32_bf16(a[km], b[ln], acc[km][ln], 0, 0, 0);
        }
        __syncthreads();
    }
#pragma unroll
    for (int km = 0; km < 2; ++km)
#pragma unroll
        for (int ln = 0; ln < 4; ++ln)
#pragma unroll
            for (int r = 0; r < 4; ++r) {
                int row = bm * 96 + wm * 32 + km * 16 + hi * 4 + r;
                int col = bn * 128 + wn * 64 + ln * 16 + l15;
                int lvl = row / (T_ * N_);
                int r2 = row - lvl * (T_ * N_);
                outp[(size_t)r2 * (4 * OUTC) + lvl * OUTC + col] = acc[km][ln][r] + b2[col];
            }
}

extern "C" void kernel_launch(void* const* d_in, const int* in_sizes, int n_in,
                              void* d_out, int out_size, void* d_ws, size_t ws_size,
                              hipStream_t stream) {
    const float* fmaps   = (const float*)d_in[0];
    const float* coords  = (const float*)d_in[1];
    const float* qcoords = (const float*)d_in[2];
    const int*   qframes = (const int*)d_in[3];
    const float* w1      = (const float*)d_in[4];
    const float* b1      = (const float*)d_in[5];
    const float* w2      = (const float*)d_in[6];
    const float* b2      = (const float*)d_in[7];
    float* outp = (float*)d_out;

    unsigned char* ws = (unsigned char*)d_ws;
    size_t off = 0;
    auto take = [&](size_t bytes) {
        unsigned char* p = ws + off;
        off += (bytes + 255) & ~(size_t)255;
        return p;
    };
    // padded pyramid buffers
    const int Hs[4] = {96, 48, 24, 12}, Wss[4] = {128, 64, 32, 16};
    unsigned short* fmraw[4];
    unsigned short* fmint[4];
    for (int l = 0; l < 4; ++l) {
        int PH = Hs[l] + 2 * PAD, PW = Wss[l] + 2 * PAD;
        fmraw[l] = (unsigned short*)take((size_t)T_ * PH * PW * D_ * 2);
        fmint[l] = fmraw[l] + ((size_t)PAD * PW + PAD) * D_;
    }
    unsigned short* tfg  = (unsigned short*)take((size_t)4 * N_ * 64 * D_ * 2);
    unsigned short* vol  = (unsigned short*)take((size_t)MTOT * K2 * 2);
    unsigned short* hbuf = (unsigned short*)take((size_t)MTOT * H1 * 2);
    unsigned short* w1t  = (unsigned short*)take((size_t)H1 * K2 * 2);
    unsigned short* w2t  = (unsigned short*)take((size_t)OUTC * H1 * 2);

    for (int l = 0; l < 4; ++l)
        hipLaunchKernelGGL(k_padzero, dim3(1024), dim3(256), 0, stream,
                           (uint4*)fmraw[l], Hs[l], Wss[l]);
    hipLaunchKernelGGL(k_w1t, dim3(6, 49), dim3(256), 0, stream, w1, w1t);
    hipLaunchKernelGGL(k_w2t, dim3((OUTC * H1 + 255) / 256), dim3(256), 0, stream, w2, w2t);
    hipLaunchKernelGGL(k_normalize, dim3(T_ * H_), dim3(256), 0, stream, fmaps, fmint[0]);
    hipLaunchKernelGGL(k_pool, dim3((T_ * 48 * 64 * 32 + 255) / 256), dim3(256), 0, stream,
                       fmint[0], fmint[1], 96, 128);
    hipLaunchKernelGGL(k_pool, dim3((T_ * 24 * 32 * 32 + 255) / 256), dim3(256), 0, stream,
                       fmint[1], fmint[2], 48, 64);
    hipLaunchKernelGGL(k_pool, dim3((T_ * 12 * 16 * 32 + 255) / 256), dim3(256), 0, stream,
                       fmint[2], fmint[3], 24, 32);

    hipLaunchKernelGGL(k_tf, dim3(N_, 4), dim3(256), 0, stream,
                       fmint[0], fmint[1], fmint[2], fmint[3], qcoords, qframes, tfg);
    hipLaunchKernelGGL(k_cfvol, dim3(N_, T_, 4), dim3(256), 0, stream,
                       fmint[0], fmint[1], fmint[2], fmint[3], coords, tfg, vol);
    hipLaunchKernelGGL(k_gemm1, dim3(512), dim3(384), 0, stream, vol, w1t, b1, hbuf);
    hipLaunchKernelGGL(k_gemm2, dim3(512), dim3(384), 0, stream, hbuf, w2t, b2, outp);
}

// Round 24
// 281.036 us; speedup vs baseline: 1.1711x; 1.0293x over previous
//
#include <hip/hip_runtime.h>
#include <hip/hip_bf16.h>
#include <stdint.h>

// Problem constants (fixed by setup_inputs)
#define T_   24
#define D_   128
#define H_   96
#define W_   128
#define N_   256
#define KP   49      // 7x7 support points
#define K2   3136    // vol K-dim: 49 k-rows x 64 l-slots (l>=49 zero-padded)
#define H1   384     // MLP hidden
#define OUTC 256     // MLP out
#define MTOT (4 * T_ * N_)   // 24576 rows batched over levels

// padded pyramid geometry (8-px zero border on all sides)
#define PAD  8

typedef __attribute__((ext_vector_type(8))) __bf16 bf16x8;
typedef __attribute__((ext_vector_type(4))) float f32x4;

typedef __attribute__((address_space(3))) unsigned int lds_u32;
typedef const __attribute__((address_space(1))) unsigned int g_u32;
#define GLOAD16(g, l) __builtin_amdgcn_global_load_lds((g_u32*)(g), (lds_u32*)(l), 16, 0, 0)

__device__ inline float bf2f(unsigned short u) {
    union { unsigned int i; float f; } v; v.i = ((unsigned int)u) << 16; return v.f;
}
__device__ inline unsigned short f2bf(float f) {
    union { float f; unsigned int i; } v; v.f = f;
    unsigned int i = v.i;
    return (unsigned short)((i + 0x7FFFu + ((i >> 16) & 1u)) >> 16);  // RNE
}
// single-instruction packed f32->bf16 (RNE); no builtin on gfx950 -> inline asm
__device__ inline unsigned int cvtpk(float lo, float hi) {
    unsigned int r;
    asm("v_cvt_pk_bf16_f32 %0, %1, %2" : "=v"(r) : "v"(lo), "v"(hi));
    return r;
}

// ---------------- pad zero: BORDER-ONLY, all 4 levels in one launch ---------
__global__ __launch_bounds__(256) void k_padzero(uint4* __restrict__ p0,
                                                 uint4* __restrict__ p1,
                                                 uint4* __restrict__ p2,
                                                 uint4* __restrict__ p3) {
    int lvl = blockIdx.y;
    uint4* fm = lvl == 0 ? p0 : lvl == 1 ? p1 : lvl == 2 ? p2 : p3;
    int Hs = H_ >> lvl, Ws = W_ >> lvl;
    int PW = Ws + 2 * PAD, PH = Hs + 2 * PAD;
    int B1 = 2 * PAD * PW;           // top+bottom band px
    int B2 = Hs * 2 * PAD;           // left+right band px
    int ppf = B1 + B2;               // border px per frame
    size_t total = (size_t)ppf * T_ * 16;
    for (size_t idx = (size_t)blockIdx.x * 256 + threadIdx.x; idx < total;
         idx += (size_t)gridDim.x * 256) {
        int u = (int)(idx & 15);
        size_t p = idx >> 4;
        int t = (int)(p / ppf);
        int q = (int)(p % ppf);
        int y, x;
        if (q < B1) {
            int half = q / (PAD * PW);            // 0 top, 1 bottom
            int r = q - half * (PAD * PW);
            y = half ? (PH - PAD + r / PW) : (r / PW);
            x = r % PW;
        } else {
            int r = q - B1;
            y = PAD + r / (2 * PAD);
            int c = r % (2 * PAD);
            x = c < PAD ? c : (PW - PAD + (c - PAD));
        }
        uint4 z = {0u, 0u, 0u, 0u};
        fm[((size_t)t * PH * PW + (size_t)y * PW + x) * 16 + u] = z;
    }
}

// ---------------- w1 transpose via LDS tile (coalesced both sides) ----------
__global__ __launch_bounds__(256) void k_w1t(const float* __restrict__ w1,
                                             unsigned short* __restrict__ w1t) {
    __shared__ float tile[64][65];
    int bn = blockIdx.x, k = blockIdx.y;       // 6 x 49
    int tid = threadIdx.x;
    int nl = tid & 63, q = tid >> 6;
#pragma unroll
    for (int i = 0; i < 16; ++i) {
        int l = q * 16 + i;
        float v = (l < KP) ? w1[((size_t)k * KP + l) * H1 + bn * 64 + nl] : 0.f;
        tile[l][nl] = v;
    }
    __syncthreads();
#pragma unroll
    for (int i = 0; i < 16; ++i) {
        int nn = q * 16 + i;
        w1t[(size_t)(bn * 64 + nn) * K2 + k * 64 + nl] = f2bf(tile[nl][nn]);
    }
}
__global__ __launch_bounds__(256) void k_w2t(const float* __restrict__ w2,
                                             unsigned short* __restrict__ w2t) {
    int idx = blockIdx.x * 256 + threadIdx.x;           // OUTC*H1
    if (idx >= OUTC * H1) return;
    int j = idx / H1, k = idx % H1;
    w2t[idx] = f2bf(w2[(size_t)k * OUTC + j]);
}

// ---------------- L2 normalize + transpose -> padded (T,H,W,D) bf16 ----------
#define PW0 (W_ + 2 * PAD)
#define FR0 ((size_t)(H_ + 2 * PAD) * PW0 * D_)
__global__ __launch_bounds__(256) void k_normalize(const float* __restrict__ fmaps,
                                                   unsigned short* __restrict__ fm0i) {
    int bid = blockIdx.x;                 // t*H_ + h
    int t = bid / H_, h = bid % H_;
    int tid = threadIdx.x;
    __shared__ float tile[64 * 129];
    __shared__ float ssumP[64][4];
    __shared__ float rs[64];
    const float* base = fmaps + (size_t)t * D_ * H_ * W_ + (size_t)h * W_;
    unsigned short* orow = fm0i + (size_t)t * FR0 + (size_t)h * (PW0 * D_);
    for (int wt = 0; wt < 2; ++wt) {
        int wl = tid & 63, dg = tid >> 6;
        float ss = 0.f;
        for (int i = 0; i < 32; ++i) {
            int d = dg * 32 + i;
            float v = base[(size_t)d * (H_ * W_) + wt * 64 + wl];
            tile[wl * 129 + d] = v;
            ss += v * v;
        }
        ssumP[wl][dg] = ss;
        __syncthreads();
        if (tid < 64)
            rs[tid] = rsqrtf(fmaxf(ssumP[tid][0] + ssumP[tid][1] + ssumP[tid][2] + ssumP[tid][3], 1e-12f));
        __syncthreads();
        int c = tid & 63, rg = tid >> 6;      // u32 col (2 d's), row group
        for (int i = 0; i < 16; ++i) {
            int wll = rg * 16 + i;
            float r = rs[wll];
            float v0 = tile[wll * 129 + c * 2] * r;
            float v1 = tile[wll * 129 + c * 2 + 1] * r;
            *(unsigned int*)(orow + (size_t)(wt * 64 + wll) * D_ + c * 2) = cvtpk(v0, v1);
        }
        __syncthreads();
    }
}

// ---------------- 2x2 avg pool on padded buffers -----------------------------
__global__ __launch_bounds__(256) void k_pool(const unsigned short* __restrict__ ini,
                                              unsigned short* __restrict__ outi,
                                              int Hs, int Ws) {
    int Ho = Hs >> 1, Wo = Ws >> 1;
    int PWi = Ws + 2 * PAD, PWo = Wo + 2 * PAD;
    size_t FRi = (size_t)(Hs + 2 * PAD) * PWi * D_;
    size_t FRo = (size_t)(Ho + 2 * PAD) * PWo * D_;
    size_t total = (size_t)T_ * Ho * Wo * (D_ / 4);
    size_t idx = (size_t)blockIdx.x * 256 + threadIdx.x;
    if (idx >= total) return;
    int d4 = idx & 31;
    size_t p = idx >> 5;
    int x = (int)(p % Wo); p /= Wo;
    int y = (int)(p % Ho); int t = (int)(p / Ho);
    const unsigned short* b0 = ini + (size_t)t * FRi + ((size_t)(2 * y) * PWi + 2 * x) * D_ + d4 * 4;
    const unsigned short* b1r = b0 + (size_t)PWi * D_;
    float acc[4] = {0.f, 0.f, 0.f, 0.f};
#pragma unroll
    for (int j = 0; j < 2; ++j) {
        const unsigned short* bb = j ? b1r : b0;
#pragma unroll
        for (int i = 0; i < 2; ++i) {
            const unsigned short* q = bb + i * D_;
#pragma unroll
            for (int c = 0; c < 4; ++c) acc[c] += bf2f(q[c]);
        }
    }
    unsigned short* o = outi + (size_t)t * FRo + ((size_t)y * PWo + x) * D_ + d4 * 4;
#pragma unroll
    for (int c = 0; c < 4; ++c) o[c] = f2bf(acc[c] * 0.25f);
}

// ---------------- track-support features: templated impl, single launch -----
template <int LVL>
__device__ __forceinline__ void tf_impl(const unsigned short* __restrict__ fmi,
                                        const float* __restrict__ qcoords,
                                        const int* __restrict__ qframes,
                                        unsigned short* __restrict__ tfg) {
    constexpr int Hs = H_ >> LVL, Ws = W_ >> LVL;
    constexpr int PW = Ws + 2 * PAD;
    constexpr size_t FR = (size_t)(Hs + 2 * PAD) * PW * D_;
    constexpr float inv = 1.0f / (float)(1 << LVL);
    int n = blockIdx.x;
    int wid = threadIdx.x >> 6, lane = threadIdx.x & 63;
    int fidx = qframes[n];
    float qx = qcoords[n * 2 + 0] * inv, qy = qcoords[n * 2 + 1] * inv;
    const unsigned short* fb = fmi + (size_t)fidx * FR;
    unsigned short* orow = tfg + ((size_t)LVL * N_ + n) * (64 * D_);
    for (int k = wid; k < 64; k += 4) {
        float acc0 = 0.f, acc1 = 0.f;
        if (k < KP) {
            float px = qx + (float)(k / 7 - 3);
            float py = qy + (float)(k % 7 - 3);
            float x0f = floorf(px), y0f = floorf(py);
            float tx = px - x0f, ty = py - y0f;
            int x0 = (int)x0f, y0 = (int)y0f;
#pragma unroll
            for (int dy = 0; dy < 2; ++dy)
#pragma unroll
                for (int dx = 0; dx < 2; ++dx) {
                    long xi = x0 + dx, yi = y0 + dy;
                    float w = (dx ? tx : 1.f - tx) * (dy ? ty : 1.f - ty);
                    unsigned int pk = *(const unsigned int*)(fb + (yi * PW + xi) * D_ + lane * 2);
                    acc0 += w * bf2f((unsigned short)(pk & 0xffffu));
                    acc1 += w * bf2f((unsigned short)(pk >> 16));
                }
        }
        *(unsigned int*)(orow + k * D_ + lane * 2) = cvtpk(acc0, acc1);
    }
}

__global__ __launch_bounds__(256) void k_tf(const unsigned short* __restrict__ f0,
                                            const unsigned short* __restrict__ f1,
                                            const unsigned short* __restrict__ f2,
                                            const unsigned short* __restrict__ f3,
                                            const float* __restrict__ qcoords,
                                            const int* __restrict__ qframes,
                                            unsigned short* __restrict__ tfg) {
    switch (blockIdx.y) {      // block-uniform branch; dims const-fold per case
        case 0: tf_impl<0>(f0, qcoords, qframes, tfg); break;
        case 1: tf_impl<1>(f1, qcoords, qframes, tfg); break;
        case 2: tf_impl<2>(f2, qcoords, qframes, tfg); break;
        default: tf_impl<3>(f3, qcoords, qframes, tfg); break;
    }
}

// ---------------- cf + 49x49 correlation: templated impl, single launch -----
// Structure: r15/r19/r21-proven staging+MFMA. Gs is f32 stride-66 (the r5-
// PROVEN combine formulation: float2 taps, scalar FMAs) overlaying the 32KB
// smem block (tfs 16KB + first 1KB of Ps) — legal because ALL tfs/Ps reads
// complete before the full __syncthreads() preceding the Gs writes (r12-
// proven barrier contract). Removes 8 bf2f/iter + 16 cvtpk vs bf16 Gs.
template <int LVL>
__device__ __forceinline__ void cfvol_impl(const unsigned short* __restrict__ fmi,
                                           const float* __restrict__ coords,
                                           const unsigned short* __restrict__ tfg,
                                           unsigned short* __restrict__ vol,
                                           unsigned char* smem) {
    constexpr int Hs = H_ >> LVL, Ws = W_ >> LVL;
    constexpr int PW = Ws + 2 * PAD;
    constexpr size_t FR = (size_t)(Hs + 2 * PAD) * PW * D_;
    constexpr float inv = 1.0f / (float)(1 << LVL);
    unsigned char* tfs = smem;               // 16KB
    unsigned char* Ps = smem + 16384;        // 16KB
    float* Gs = (float*)smem;                // f32 64 x 66 = 16.9KB overlay
    int n = blockIdx.x, t = blockIdx.y;
    int tid = threadIdx.x, wid = tid >> 6, lane = tid & 63;
    int l15 = lane & 15, hi = lane >> 4;

    float cx = coords[((size_t)t * N_ + n) * 2 + 0] * inv;
    float cy = coords[((size_t)t * N_ + n) * 2 + 1] * inv;
    float fx = floorf(cx), fy = floorf(cy);
    float tx = cx - fx, ty = cy - fy;
    long bx = (long)(int)fx - 3, by = (long)(int)fy - 3;
    const unsigned short* fb = fmi + (size_t)t * FR;
    const unsigned short* tfn = tfg + ((size_t)LVL * N_ + n) * (64 * D_);
    // stage tf (16 gload16, 4/wave); LDS linear, source pre-swizzled
#pragma unroll
    for (int i = 0; i < 4; ++i) {
        int rr = wid * 16 + i * 4 + hi;
        int u = l15 ^ (rr & 7);
        GLOAD16(tfn + rr * 128 + u * 8, tfs + (wid * 4 + i) * 1024);
    }
    // stage P: row rr -> pixel (a = rr>>3, b = rr&7)
#pragma unroll
    for (int i = 0; i < 4; ++i) {
        int rr = wid * 16 + i * 4 + hi;
        int u = l15 ^ (rr & 7);
        GLOAD16(fb + ((by + (rr & 7)) * (long)PW + (bx + (rr >> 3))) * D_ + u * 8,
                Ps + (wid * 4 + i) * 1024);
    }
    asm volatile("s_waitcnt vmcnt(0)" ::: "memory");
    __builtin_amdgcn_s_barrier();
    // G = P . tf^T : wave wid computes G rows [wid*16, wid*16+16)
    f32x4 acc[4] = {f32x4{0,0,0,0}, f32x4{0,0,0,0}, f32x4{0,0,0,0}, f32x4{0,0,0,0}};
#pragma unroll
    for (int ks = 0; ks < 4; ++ks) {
        int colb = ks * 64 + hi * 16;
        int arow = wid * 16 + l15;
        bf16x8 a = *(const bf16x8*)(Ps + arow * 256 + (colb ^ ((arow & 7) << 4)));
#pragma unroll
        for (int ln = 0; ln < 4; ++ln) {
            int brow = ln * 16 + l15;
            bf16x8 b = *(const bf16x8*)(tfs + brow * 256 + (colb ^ ((brow & 7) << 4)));
            acc[ln] = __builtin_amdgcn_mfma_f32_16x16x32_bf16(a, b, acc[ln], 0, 0, 0);
        }
    }
    __syncthreads();   // ALL tfs/Ps reads complete before overlay writes
#pragma unroll
    for (int ln = 0; ln < 4; ++ln)
#pragma unroll
        for (int r = 0; r < 4; ++r)
            Gs[(wid * 16 + hi * 4 + r) * 66 + ln * 16 + l15] = acc[ln][r];
    __syncthreads();
    // combine (r5-proven float form): vol[k*64+l] = 4-tap weighted sum
    unsigned int* vrow = (unsigned int*)(vol + (((size_t)LVL * T_ + t) * N_ + n) * K2);
    float w00 = (1.f - tx) * (1.f - ty), w01 = (1.f - tx) * ty;
    float w10 = tx * (1.f - ty), w11 = tx * ty;
    int lh = lane >> 5, ll = lane & 31;
#pragma unroll
    for (int it = 0; it < 7; ++it) {
        int k = it * 8 + wid * 2 + lh;
        if (k < KP) {
            int a0 = k / 7, b0 = k - a0 * 7;
            int g = a0 * 8 + b0;
            const float* gp = &Gs[g * 66 + ll * 2];
            float2 v00 = *(const float2*)gp;
            float2 v01 = *(const float2*)(gp + 66);
            float2 v10 = *(const float2*)(gp + 8 * 66);
            float2 v11 = *(const float2*)(gp + 9 * 66);
            float r0 = w00 * v00.x + w01 * v01.x + w10 * v10.x + w11 * v11.x;
            float r1 = w00 * v00.y + w01 * v01.y + w10 * v10.y + w11 * v11.y;
            vrow[k * 32 + ll] = cvtpk(r0, r1);
        }
    }
}

__global__ __launch_bounds__(256) void k_cfvol(const unsigned short* __restrict__ f0,
                                               const unsigned short* __restrict__ f1,
                                               const unsigned short* __restrict__ f2,
                                               const unsigned short* __restrict__ f3,
                                               const float* __restrict__ coords,
                                               const unsigned short* __restrict__ tfg,
                                               unsigned short* __restrict__ vol) {
    __shared__ unsigned char smem[32768];
    switch (blockIdx.z) {      // block-uniform; dims const-fold per case
        case 0: cfvol_impl<0>(f0, coords, tfg, vol, smem); break;
        case 1: cfvol_impl<1>(f1, coords, tfg, vol, smem); break;
        case 2: cfvol_impl<2>(f2, coords, tfg, vol, smem); break;
        default: cfvol_impl<3>(f3, coords, tfg, vol, smem); break;
    }
}

// ---------------- GEMM1: (24576 x K2) @ w1t^T (384 x K2), BM=96 BN=192 -------
// Grid 512 = exactly 2 tail-free rounds of 256 CUs. 384 thr (6 waves 3x2,
// 24 MFMA/step). Single-buffer {stage, syncthreads, MFMA, syncthreads},
// 128B-row XOR swizzle, XCD swizzle. LDS 36KB. (r23-proven)
__global__ __launch_bounds__(384) void k_gemm1(const unsigned short* __restrict__ A,
                                               const unsigned short* __restrict__ Bt,
                                               const float* __restrict__ b1,
                                               unsigned short* __restrict__ Hout) {
    __shared__ unsigned char As[12288];   // 96 rows x 128B, swizzled content
    __shared__ unsigned char Bs[24576];   // 192 rows x 128B
    int bid = blockIdx.x;                           // nwg = 512 = 8 * 64
    int swz = (bid & 7) * 64 + (bid >> 3);
    int bm = swz >> 1, bn = swz & 1;
    int tid = threadIdx.x, lane = tid & 63;
    int wid = tid >> 6;                   // 0..5
    int wm = wid >> 1, wn = wid & 1;      // 3 x 2 wave grid
    int l15 = lane & 15, hi = lane >> 4;
    f32x4 acc[2][6] = {};
    const unsigned short* Abase = A + (size_t)(bm * 96) * K2;
    const unsigned short* Bbase = Bt + (size_t)(bn * 192) * K2;
    for (int kt = 0; kt < K2 / 64; ++kt) {        // 49
#pragma unroll
        for (int q = 0; q < 2; ++q) {             // A: 96 rows x 8 units = 768
            int e = q * 384 + tid;
            int row = e >> 3, su = (e & 7) ^ (row & 7);
            GLOAD16(Abase + (size_t)row * K2 + kt * 64 + su * 8,
                    As + q * 6144 + wid * 1024);
        }
#pragma unroll
        for (int q = 0; q < 4; ++q) {             // B: 192 rows x 8 units = 1536
            int e = q * 384 + tid;
            int row = e >> 3, su = (e & 7) ^ (row & 7);
            GLOAD16(Bbase + (size_t)row * K2 + kt * 64 + su * 8,
                    Bs + q * 6144 + wid * 1024);
        }
        __syncthreads();
#pragma unroll
        for (int ks = 0; ks < 2; ++ks) {
            int colb = ks * 64 + hi * 16;
            bf16x8 a[2], b[6];
#pragma unroll
            for (int km = 0; km < 2; ++km) {
                int arow = wm * 32 + km * 16 + l15;
                a[km] = *(const bf16x8*)(As + arow * 128 + (colb ^ ((arow & 7) << 4)));
            }
#pragma unroll
            for (int ln = 0; ln < 6; ++ln) {
                int brow = wn * 96 + ln * 16 + l15;
                b[ln] = *(const bf16x8*)(Bs + brow * 128 + (colb ^ ((brow & 7) << 4)));
            }
#pragma unroll
            for (int km = 0; km < 2; ++km)
#pragma unroll
                for (int ln = 0; ln < 6; ++ln)
                    acc[km][ln] = __builtin_amdgcn_mfma_f32_16x16x32_bf16(a[km], b[ln], acc[km][ln], 0, 0, 0);
        }
        __syncthreads();
    }
#pragma unroll
    for (int km = 0; km < 2; ++km)
#pragma unroll
        for (int ln = 0; ln < 6; ++ln)
#pragma unroll
            for (int r = 0; r < 4; ++r) {
                int row = bm * 96 + wm * 32 + km * 16 + hi * 4 + r;
                int col = bn * 192 + wn * 96 + ln * 16 + l15;
                float x = acc[km][ln][r] + b1[col];
                float g = 0.5f * x * (1.f + erff(x * 0.70710678118654752f));
                Hout[(size_t)row * H1 + col] = f2bf(g);
            }
}

// ---------------- GEMM2: (24576 x 384) @ w2t^T (256 x 384), BM=96 BN=128 -----
// Grid 512 = exactly 2 waves of 256 CUs. (r19-proven)
__global__ __launch_bounds__(384) void k_gemm2(const unsigned short* __restrict__ A,
                                               const unsigned short* __restrict__ Bt,
                                               const float* __restrict__ b2,
                                               float* __restrict__ outp) {
    __shared__ unsigned char As[12288];   // 96 x 128B
    __shared__ unsigned char Bs[16384];   // 128 x 128B
    int bid = blockIdx.x;                           // nwg = 512 = 8 * 64
    int swz = (bid & 7) * 64 + (bid >> 3);
    int bm = swz >> 1, bn = swz & 1;
    int tid = threadIdx.x, lane = tid & 63;
    int wid = tid >> 6;
    int wm = wid >> 1, wn = wid & 1;      // 3 x 2
    int l15 = lane & 15, hi = lane >> 4;
    f32x4 acc[2][4] = {};
    const unsigned short* Abase = A + (size_t)(bm * 96) * H1;
    const unsigned short* Bbase = Bt + (size_t)(bn * 128) * H1;
    for (int kt = 0; kt < H1 / 64; ++kt) {        // 6
#pragma unroll
        for (int q = 0; q < 2; ++q) {             // A: 96 x 8 units = 768
            int e = q * 384 + tid;
            int row = e >> 3, su = (e & 7) ^ (row & 7);
            GLOAD16(Abase + (size_t)row * H1 + kt * 64 + su * 8,
                    As + q * 6144 + wid * 1024);
        }
#pragma unroll
        for (int q = 0; q < 3; ++q) {             // B: 128 x 8 units = 1024
            if (q < 2 || tid < 256) {
                int e = q * 384 + tid;
                int row = e >> 3, su = (e & 7) ^ (row & 7);
                GLOAD16(Bbase + (size_t)row * H1 + kt * 64 + su * 8,
                        Bs + q * 6144 + wid * 1024);
            }
        }
        __syncthreads();
#pragma unroll
        for (int ks = 0; ks < 2; ++ks) {
            int colb = ks * 64 + hi * 16;
            bf16x8 a[2], b[4];
#pragma unroll
            for (int km = 0; km < 2; ++km) {
                int arow = wm * 32 + km * 16 + l15;
                a[km] = *(const bf16x8*)(As + arow * 128 + (colb ^ ((arow & 7) << 4)));
            }
#pragma unroll
            for (int ln = 0; ln < 4; ++ln) {
                int brow = wn * 64 + ln * 16 + l15;
                b[ln] = *(const bf16x8*)(Bs + brow * 128 + (colb ^ ((brow & 7) << 4)));
            }
#pragma unroll
            for (int km = 0; km < 2; ++km)
#pragma unroll
                for (int ln = 0; ln < 4; ++ln)
                    acc[km][ln] = __builtin_amdgcn_mfma_f32_16x16x32_bf16(a[km], b[ln], acc[km][ln], 0, 0, 0);
        }
        __syncthreads();
    }
#pragma unroll
    for (int km = 0; km < 2; ++km)
#pragma unroll
        for (int ln = 0; ln < 4; ++ln)
#pragma unroll
            for (int r = 0; r < 4; ++r) {
                int row = bm * 96 + wm * 32 + km * 16 + hi * 4 + r;
                int col = bn * 128 + wn * 64 + ln * 16 + l15;
                int lvl = row / (T_ * N_);
                int r2 = row - lvl * (T_ * N_);
                outp[(size_t)r2 * (4 * OUTC) + lvl * OUTC + col] = acc[km][ln][r] + b2[col];
            }
}

extern "C" void kernel_launch(void* const* d_in, const int* in_sizes, int n_in,
                              void* d_out, int out_size, void* d_ws, size_t ws_size,
                              hipStream_t stream) {
    const float* fmaps   = (const float*)d_in[0];
    const float* coords  = (const float*)d_in[1];
    const float* qcoords = (const float*)d_in[2];
    const int*   qframes = (const int*)d_in[3];
    const float* w1      = (const float*)d_in[4];
    const float* b1      = (const float*)d_in[5];
    const float* w2      = (const float*)d_in[6];
    const float* b2      = (const float*)d_in[7];
    float* outp = (float*)d_out;

    unsigned char* ws = (unsigned char*)d_ws;
    size_t off = 0;
    auto take = [&](size_t bytes) {
        unsigned char* p = ws + off;
        off += (bytes + 255) & ~(size_t)255;
        return p;
    };
    // padded pyramid buffers
    const int Hs[4] = {96, 48, 24, 12}, Wss[4] = {128, 64, 32, 16};
    unsigned short* fmraw[4];
    unsigned short* fmint[4];
    for (int l = 0; l < 4; ++l) {
        int PH = Hs[l] + 2 * PAD, PW = Wss[l] + 2 * PAD;
        fmraw[l] = (unsigned short*)take((size_t)T_ * PH * PW * D_ * 2);
        fmint[l] = fmraw[l] + ((size_t)PAD * PW + PAD) * D_;
    }
    unsigned short* tfg  = (unsigned short*)take((size_t)4 * N_ * 64 * D_ * 2);
    unsigned short* vol  = (unsigned short*)take((size_t)MTOT * K2 * 2);
    unsigned short* hbuf = (unsigned short*)take((size_t)MTOT * H1 * 2);
    unsigned short* w1t  = (unsigned short*)take((size_t)H1 * K2 * 2);
    unsigned short* w2t  = (unsigned short*)take((size_t)OUTC * H1 * 2);

    hipLaunchKernelGGL(k_padzero, dim3(256, 4), dim3(256), 0, stream,
                       (uint4*)fmraw[0], (uint4*)fmraw[1], (uint4*)fmraw[2], (uint4*)fmraw[3]);
    hipLaunchKernelGGL(k_w1t, dim3(6, 49), dim3(256), 0, stream, w1, w1t);
    hipLaunchKernelGGL(k_w2t, dim3((OUTC * H1 + 255) / 256), dim3(256), 0, stream, w2, w2t);
    hipLaunchKernelGGL(k_normalize, dim3(T_ * H_), dim3(256), 0, stream, fmaps, fmint[0]);
    hipLaunchKernelGGL(k_pool, dim3((T_ * 48 * 64 * 32 + 255) / 256), dim3(256), 0, stream,
                       fmint[0], fmint[1], 96, 128);
    hipLaunchKernelGGL(k_pool, dim3((T_ * 24 * 32 * 32 + 255) / 256), dim3(256), 0, stream,
                       fmint[1], fmint[2], 48, 64);
    hipLaunchKernelGGL(k_pool, dim3((T_ * 12 * 16 * 32 + 255) / 256), dim3(256), 0, stream,
                       fmint[2], fmint[3], 24, 32);

    hipLaunchKernelGGL(k_tf, dim3(N_, 4), dim3(256), 0, stream,
                       fmint[0], fmint[1], fmint[2], fmint[3], qcoords, qframes, tfg);
    hipLaunchKernelGGL(k_cfvol, dim3(N_, T_, 4), dim3(256), 0, stream,
                       fmint[0], fmint[1], fmint[2], fmint[3], coords, tfg, vol);
    hipLaunchKernelGGL(k_gemm1, dim3(512), dim3(384), 0, stream, vol, w1t, b1, hbuf);
    hipLaunchKernelGGL(k_gemm2, dim3(512), dim3(384), 0, stream, hbuf, w2t, b2, outp);
}

// Round 25
// 277.064 us; speedup vs baseline: 1.1879x; 1.0143x over previous
//
#include <hip/hip_runtime.h>
#include <hip/hip_bf16.h>
#include <stdint.h>

// Problem constants (fixed by setup_inputs)
#define T_   24
#define D_   128
#define H_   96
#define W_   128
#define N_   256
#define KP   49      // 7x7 support points
#define K2   3136    // vol K-dim: 49 k-rows x 64 l-slots (l>=49 zero-padded)
#define H1   384     // MLP hidden
#define OUTC 256     // MLP out
#define MTOT (4 * T_ * N_)   // 24576 rows batched over levels

// padded pyramid geometry (8-px zero border on all sides)
#define PAD  8

typedef __attribute__((ext_vector_type(8))) __bf16 bf16x8;
typedef __attribute__((ext_vector_type(4))) float f32x4;

typedef __attribute__((address_space(3))) unsigned int lds_u32;
typedef const __attribute__((address_space(1))) unsigned int g_u32;
#define GLOAD16(g, l) __builtin_amdgcn_global_load_lds((g_u32*)(g), (lds_u32*)(l), 16, 0, 0)

__device__ inline float bf2f(unsigned short u) {
    union { unsigned int i; float f; } v; v.i = ((unsigned int)u) << 16; return v.f;
}
__device__ inline unsigned short f2bf(float f) {
    union { float f; unsigned int i; } v; v.f = f;
    unsigned int i = v.i;
    return (unsigned short)((i + 0x7FFFu + ((i >> 16) & 1u)) >> 16);  // RNE
}
// single-instruction packed f32->bf16 (RNE); no builtin on gfx950 -> inline asm
__device__ inline unsigned int cvtpk(float lo, float hi) {
    unsigned int r;
    asm("v_cvt_pk_bf16_f32 %0, %1, %2" : "=v"(r) : "v"(lo), "v"(hi));
    return r;
}

// ---------------- pad zero: BORDER-ONLY, all 4 levels in one launch ---------
__global__ __launch_bounds__(256) void k_padzero(uint4* __restrict__ p0,
                                                 uint4* __restrict__ p1,
                                                 uint4* __restrict__ p2,
                                                 uint4* __restrict__ p3) {
    int lvl = blockIdx.y;
    uint4* fm = lvl == 0 ? p0 : lvl == 1 ? p1 : lvl == 2 ? p2 : p3;
    int Hs = H_ >> lvl, Ws = W_ >> lvl;
    int PW = Ws + 2 * PAD, PH = Hs + 2 * PAD;
    int B1 = 2 * PAD * PW;           // top+bottom band px
    int B2 = Hs * 2 * PAD;           // left+right band px
    int ppf = B1 + B2;               // border px per frame
    size_t total = (size_t)ppf * T_ * 16;
    for (size_t idx = (size_t)blockIdx.x * 256 + threadIdx.x; idx < total;
         idx += (size_t)gridDim.x * 256) {
        int u = (int)(idx & 15);
        size_t p = idx >> 4;
        int t = (int)(p / ppf);
        int q = (int)(p % ppf);
        int y, x;
        if (q < B1) {
            int half = q / (PAD * PW);            // 0 top, 1 bottom
            int r = q - half * (PAD * PW);
            y = half ? (PH - PAD + r / PW) : (r / PW);
            x = r % PW;
        } else {
            int r = q - B1;
            y = PAD + r / (2 * PAD);
            int c = r % (2 * PAD);
            x = c < PAD ? c : (PW - PAD + (c - PAD));
        }
        uint4 z = {0u, 0u, 0u, 0u};
        fm[((size_t)t * PH * PW + (size_t)y * PW + x) * 16 + u] = z;
    }
}

// ---------------- w1 transpose via LDS tile (coalesced both sides) ----------
__global__ __launch_bounds__(256) void k_w1t(const float* __restrict__ w1,
                                             unsigned short* __restrict__ w1t) {
    __shared__ float tile[64][65];
    int bn = blockIdx.x, k = blockIdx.y;       // 6 x 49
    int tid = threadIdx.x;
    int nl = tid & 63, q = tid >> 6;
#pragma unroll
    for (int i = 0; i < 16; ++i) {
        int l = q * 16 + i;
        float v = (l < KP) ? w1[((size_t)k * KP + l) * H1 + bn * 64 + nl] : 0.f;
        tile[l][nl] = v;
    }
    __syncthreads();
#pragma unroll
    for (int i = 0; i < 16; ++i) {
        int nn = q * 16 + i;
        w1t[(size_t)(bn * 64 + nn) * K2 + k * 64 + nl] = f2bf(tile[nl][nn]);
    }
}
__global__ __launch_bounds__(256) void k_w2t(const float* __restrict__ w2,
                                             unsigned short* __restrict__ w2t) {
    int idx = blockIdx.x * 256 + threadIdx.x;           // OUTC*H1
    if (idx >= OUTC * H1) return;
    int j = idx / H1, k = idx % H1;
    w2t[idx] = f2bf(w2[(size_t)k * OUTC + j]);
}

// ---------------- L2 normalize + transpose -> padded (T,H,W,D) bf16 ----------
#define PW0 (W_ + 2 * PAD)
#define FR0 ((size_t)(H_ + 2 * PAD) * PW0 * D_)
__global__ __launch_bounds__(256) void k_normalize(const float* __restrict__ fmaps,
                                                   unsigned short* __restrict__ fm0i) {
    int bid = blockIdx.x;                 // t*H_ + h
    int t = bid / H_, h = bid % H_;
    int tid = threadIdx.x;
    __shared__ float tile[64 * 129];
    __shared__ float ssumP[64][4];
    __shared__ float rs[64];
    const float* base = fmaps + (size_t)t * D_ * H_ * W_ + (size_t)h * W_;
    unsigned short* orow = fm0i + (size_t)t * FR0 + (size_t)h * (PW0 * D_);
    for (int wt = 0; wt < 2; ++wt) {
        int wl = tid & 63, dg = tid >> 6;
        float ss = 0.f;
        for (int i = 0; i < 32; ++i) {
            int d = dg * 32 + i;
            float v = base[(size_t)d * (H_ * W_) + wt * 64 + wl];
            tile[wl * 129 + d] = v;
            ss += v * v;
        }
        ssumP[wl][dg] = ss;
        __syncthreads();
        if (tid < 64)
            rs[tid] = rsqrtf(fmaxf(ssumP[tid][0] + ssumP[tid][1] + ssumP[tid][2] + ssumP[tid][3], 1e-12f));
        __syncthreads();
        int c = tid & 63, rg = tid >> 6;      // u32 col (2 d's), row group
        for (int i = 0; i < 16; ++i) {
            int wll = rg * 16 + i;
            float r = rs[wll];
            float v0 = tile[wll * 129 + c * 2] * r;
            float v1 = tile[wll * 129 + c * 2 + 1] * r;
            *(unsigned int*)(orow + (size_t)(wt * 64 + wll) * D_ + c * 2) = cvtpk(v0, v1);
        }
        __syncthreads();
    }
}

// ---------------- 2x2 avg pool on padded buffers -----------------------------
__global__ __launch_bounds__(256) void k_pool(const unsigned short* __restrict__ ini,
                                              unsigned short* __restrict__ outi,
                                              int Hs, int Ws) {
    int Ho = Hs >> 1, Wo = Ws >> 1;
    int PWi = Ws + 2 * PAD, PWo = Wo + 2 * PAD;
    size_t FRi = (size_t)(Hs + 2 * PAD) * PWi * D_;
    size_t FRo = (size_t)(Ho + 2 * PAD) * PWo * D_;
    size_t total = (size_t)T_ * Ho * Wo * (D_ / 4);
    size_t idx = (size_t)blockIdx.x * 256 + threadIdx.x;
    if (idx >= total) return;
    int d4 = idx & 31;
    size_t p = idx >> 5;
    int x = (int)(p % Wo); p /= Wo;
    int y = (int)(p % Ho); int t = (int)(p / Ho);
    const unsigned short* b0 = ini + (size_t)t * FRi + ((size_t)(2 * y) * PWi + 2 * x) * D_ + d4 * 4;
    const unsigned short* b1r = b0 + (size_t)PWi * D_;
    float acc[4] = {0.f, 0.f, 0.f, 0.f};
#pragma unroll
    for (int j = 0; j < 2; ++j) {
        const unsigned short* bb = j ? b1r : b0;
#pragma unroll
        for (int i = 0; i < 2; ++i) {
            const unsigned short* q = bb + i * D_;
#pragma unroll
            for (int c = 0; c < 4; ++c) acc[c] += bf2f(q[c]);
        }
    }
    unsigned short* o = outi + (size_t)t * FRo + ((size_t)y * PWo + x) * D_ + d4 * 4;
#pragma unroll
    for (int c = 0; c < 4; ++c) o[c] = f2bf(acc[c] * 0.25f);
}

// ---------------- track-support features: templated impl, single launch -----
template <int LVL>
__device__ __forceinline__ void tf_impl(const unsigned short* __restrict__ fmi,
                                        const float* __restrict__ qcoords,
                                        const int* __restrict__ qframes,
                                        unsigned short* __restrict__ tfg) {
    constexpr int Hs = H_ >> LVL, Ws = W_ >> LVL;
    constexpr int PW = Ws + 2 * PAD;
    constexpr size_t FR = (size_t)(Hs + 2 * PAD) * PW * D_;
    constexpr float inv = 1.0f / (float)(1 << LVL);
    int n = blockIdx.x;
    int wid = threadIdx.x >> 6, lane = threadIdx.x & 63;
    int fidx = qframes[n];
    float qx = qcoords[n * 2 + 0] * inv, qy = qcoords[n * 2 + 1] * inv;
    const unsigned short* fb = fmi + (size_t)fidx * FR;
    unsigned short* orow = tfg + ((size_t)LVL * N_ + n) * (64 * D_);
    for (int k = wid; k < 64; k += 4) {
        float acc0 = 0.f, acc1 = 0.f;
        if (k < KP) {
            float px = qx + (float)(k / 7 - 3);
            float py = qy + (float)(k % 7 - 3);
            float x0f = floorf(px), y0f = floorf(py);
            float tx = px - x0f, ty = py - y0f;
            int x0 = (int)x0f, y0 = (int)y0f;
#pragma unroll
            for (int dy = 0; dy < 2; ++dy)
#pragma unroll
                for (int dx = 0; dx < 2; ++dx) {
                    long xi = x0 + dx, yi = y0 + dy;
                    float w = (dx ? tx : 1.f - tx) * (dy ? ty : 1.f - ty);
                    unsigned int pk = *(const unsigned int*)(fb + (yi * PW + xi) * D_ + lane * 2);
                    acc0 += w * bf2f((unsigned short)(pk & 0xffffu));
                    acc1 += w * bf2f((unsigned short)(pk >> 16));
                }
        }
        *(unsigned int*)(orow + k * D_ + lane * 2) = cvtpk(acc0, acc1);
    }
}

__global__ __launch_bounds__(256) void k_tf(const unsigned short* __restrict__ f0,
                                            const unsigned short* __restrict__ f1,
                                            const unsigned short* __restrict__ f2,
                                            const unsigned short* __restrict__ f3,
                                            const float* __restrict__ qcoords,
                                            const int* __restrict__ qframes,
                                            unsigned short* __restrict__ tfg) {
    switch (blockIdx.y) {      // block-uniform branch; dims const-fold per case
        case 0: tf_impl<0>(f0, qcoords, qframes, tfg); break;
        case 1: tf_impl<1>(f1, qcoords, qframes, tfg); break;
        case 2: tf_impl<2>(f2, qcoords, qframes, tfg); break;
        default: tf_impl<3>(f3, qcoords, qframes, tfg); break;
    }
}

// ---------------- cf + 49x49 correlation: 2 t per block, shared tf ----------
// 512 thr (8 waves). Waves 0-3 handle t0 = 2*blockIdx.y, waves 4-7 handle t1.
// tf staged ONCE (by waves 0-3) and shared by both halves — cross-wave tf
// reads are guarded by the r5/r9-proven vmcnt(0)+s_barrier contract (same as
// the existing 4-wave sharing). Per-half Gs (f32 stride 66, r24-proven
// combine VERBATIM, wid->wl rename only). Gs0 overlays tfs+Ps0; Gs1 overlays
// Ps1+tail. smem 49664B -> 3 blocks/CU x 8 waves = 24 waves/CU. Halves the
// serial block count (24576 -> 12288) and tf L2 traffic.
template <int LVL>
__device__ __forceinline__ void cfvol_impl(const unsigned short* __restrict__ fmi,
                                           const float* __restrict__ coords,
                                           const unsigned short* __restrict__ tfg,
                                           unsigned short* __restrict__ vol,
                                           unsigned char* smem) {
    constexpr int Hs = H_ >> LVL, Ws = W_ >> LVL;
    constexpr int PW = Ws + 2 * PAD;
    constexpr size_t FR = (size_t)(Hs + 2 * PAD) * PW * D_;
    constexpr float inv = 1.0f / (float)(1 << LVL);
    unsigned char* tfs = smem;                   // 16KB (staged by waves 0-3)
    int n = blockIdx.x;
    int tid = threadIdx.x, wid = tid >> 6, lane = tid & 63;
    int half = wid >> 2, wl = wid & 3;           // half: which t; wl: wave in half
    int t = blockIdx.y * 2 + half;
    unsigned char* Ps = smem + 16384 + half * 16384;          // per-half P
    float* Gs = half ? (float*)(smem + 32768) : (float*)smem; // per-half G overlay
    int l15 = lane & 15, hi = lane >> 4;

    float cx = coords[((size_t)t * N_ + n) * 2 + 0] * inv;
    float cy = coords[((size_t)t * N_ + n) * 2 + 1] * inv;
    float fx = floorf(cx), fy = floorf(cy);
    float tx = cx - fx, ty = cy - fy;
    long bx = (long)(int)fx - 3, by = (long)(int)fy - 3;
    const unsigned short* fb = fmi + (size_t)t * FR;
    const unsigned short* tfn = tfg + ((size_t)LVL * N_ + n) * (64 * D_);
    // stage tf (waves 0-3 only; 16 gload16); LDS linear, source pre-swizzled
    if (half == 0) {
#pragma unroll
        for (int i = 0; i < 4; ++i) {
            int rr = wl * 16 + i * 4 + hi;
            int u = l15 ^ (rr & 7);
            GLOAD16(tfn + rr * 128 + u * 8, tfs + (wl * 4 + i) * 1024);
        }
    }
    // stage P (both halves, own buffer): row rr -> pixel (a = rr>>3, b = rr&7)
#pragma unroll
    for (int i = 0; i < 4; ++i) {
        int rr = wl * 16 + i * 4 + hi;
        int u = l15 ^ (rr & 7);
        GLOAD16(fb + ((by + (rr & 7)) * (long)PW + (bx + (rr >> 3))) * D_ + u * 8,
                Ps + (wl * 4 + i) * 1024);
    }
    asm volatile("s_waitcnt vmcnt(0)" ::: "memory");
    __builtin_amdgcn_s_barrier();
    // G = P . tf^T : wave wl of each half computes G rows [wl*16, wl*16+16)
    f32x4 acc[4] = {f32x4{0,0,0,0}, f32x4{0,0,0,0}, f32x4{0,0,0,0}, f32x4{0,0,0,0}};
#pragma unroll
    for (int ks = 0; ks < 4; ++ks) {
        int colb = ks * 64 + hi * 16;
        int arow = wl * 16 + l15;
        bf16x8 a = *(const bf16x8*)(Ps + arow * 256 + (colb ^ ((arow & 7) << 4)));
#pragma unroll
        for (int ln = 0; ln < 4; ++ln) {
            int brow = ln * 16 + l15;
            bf16x8 b = *(const bf16x8*)(tfs + brow * 256 + (colb ^ ((brow & 7) << 4)));
            acc[ln] = __builtin_amdgcn_mfma_f32_16x16x32_bf16(a, b, acc[ln], 0, 0, 0);
        }
    }
    __syncthreads();   // ALL tfs/Ps reads complete before overlay writes
#pragma unroll
    for (int ln = 0; ln < 4; ++ln)
#pragma unroll
        for (int r = 0; r < 4; ++r)
            Gs[(wl * 16 + hi * 4 + r) * 66 + ln * 16 + l15] = acc[ln][r];
    __syncthreads();
    // combine (r24-proven float form, wid->wl): vol[k*64+l] = 4-tap sum
    unsigned int* vrow = (unsigned int*)(vol + (((size_t)LVL * T_ + t) * N_ + n) * K2);
    float w00 = (1.f - tx) * (1.f - ty), w01 = (1.f - tx) * ty;
    float w10 = tx * (1.f - ty), w11 = tx * ty;
    int lh = lane >> 5, ll = lane & 31;
#pragma unroll
    for (int it = 0; it < 7; ++it) {
        int k = it * 8 + wl * 2 + lh;
        if (k < KP) {
            int a0 = k / 7, b0 = k - a0 * 7;
            int g = a0 * 8 + b0;
            const float* gp = &Gs[g * 66 + ll * 2];
            float2 v00 = *(const float2*)gp;
            float2 v01 = *(const float2*)(gp + 66);
            float2 v10 = *(const float2*)(gp + 8 * 66);
            float2 v11 = *(const float2*)(gp + 9 * 66);
            float r0 = w00 * v00.x + w01 * v01.x + w10 * v10.x + w11 * v11.x;
            float r1 = w00 * v00.y + w01 * v01.y + w10 * v10.y + w11 * v11.y;
            vrow[k * 32 + ll] = cvtpk(r0, r1);
        }
    }
}

__global__ __launch_bounds__(512) void k_cfvol(const unsigned short* __restrict__ f0,
                                               const unsigned short* __restrict__ f1,
                                               const unsigned short* __restrict__ f2,
                                               const unsigned short* __restrict__ f3,
                                               const float* __restrict__ coords,
                                               const unsigned short* __restrict__ tfg,
                                               unsigned short* __restrict__ vol) {
    __shared__ unsigned char smem[49664];   // tfs 16K | Ps0 16K | Ps1 16K + G1 tail
    switch (blockIdx.z) {      // block-uniform; dims const-fold per case
        case 0: cfvol_impl<0>(f0, coords, tfg, vol, smem); break;
        case 1: cfvol_impl<1>(f1, coords, tfg, vol, smem); break;
        case 2: cfvol_impl<2>(f2, coords, tfg, vol, smem); break;
        default: cfvol_impl<3>(f3, coords, tfg, vol, smem); break;
    }
}

// ---------------- GEMM1: (24576 x K2) @ w1t^T (384 x K2), BM=96 BN=192 -------
// Grid 512 = exactly 2 tail-free rounds of 256 CUs. 384 thr (6 waves 3x2,
// 24 MFMA/step). Single-buffer {stage, syncthreads, MFMA, syncthreads},
// 128B-row XOR swizzle, XCD swizzle. LDS 36KB. (r23-proven)
__global__ __launch_bounds__(384) void k_gemm1(const unsigned short* __restrict__ A,
                                               const unsigned short* __restrict__ Bt,
                                               const float* __restrict__ b1,
                                               unsigned short* __restrict__ Hout) {
    __shared__ unsigned char As[12288];   // 96 rows x 128B, swizzled content
    __shared__ unsigned char Bs[24576];   // 192 rows x 128B
    int bid = blockIdx.x;                           // nwg = 512 = 8 * 64
    int swz = (bid & 7) * 64 + (bid >> 3);
    int bm = swz >> 1, bn = swz & 1;
    int tid = threadIdx.x, lane = tid & 63;
    int wid = tid >> 6;                   // 0..5
    int wm = wid >> 1, wn = wid & 1;      // 3 x 2 wave grid
    int l15 = lane & 15, hi = lane >> 4;
    f32x4 acc[2][6] = {};
    const unsigned short* Abase = A + (size_t)(bm * 96) * K2;
    const unsigned short* Bbase = Bt + (size_t)(bn * 192) * K2;
    for (int kt = 0; kt < K2 / 64; ++kt) {        // 49
#pragma unroll
        for (int q = 0; q < 2; ++q) {             // A: 96 rows x 8 units = 768
            int e = q * 384 + tid;
            int row = e >> 3, su = (e & 7) ^ (row & 7);
            GLOAD16(Abase + (size_t)row * K2 + kt * 64 + su * 8,
                    As + q * 6144 + wid * 1024);
        }
#pragma unroll
        for (int q = 0; q < 4; ++q) {             // B: 192 rows x 8 units = 1536
            int e = q * 384 + tid;
            int row = e >> 3, su = (e & 7) ^ (row & 7);
            GLOAD16(Bbase + (size_t)row * K2 + kt * 64 + su * 8,
                    Bs + q * 6144 + wid * 1024);
        }
        __syncthreads();
#pragma unroll
        for (int ks = 0; ks < 2; ++ks) {
            int colb = ks * 64 + hi * 16;
            bf16x8 a[2], b[6];
#pragma unroll
            for (int km = 0; km < 2; ++km) {
                int arow = wm * 32 + km * 16 + l15;
                a[km] = *(const bf16x8*)(As + arow * 128 + (colb ^ ((arow & 7) << 4)));
            }
#pragma unroll
            for (int ln = 0; ln < 6; ++ln) {
                int brow = wn * 96 + ln * 16 + l15;
                b[ln] = *(const bf16x8*)(Bs + brow * 128 + (colb ^ ((brow & 7) << 4)));
            }
#pragma unroll
            for (int km = 0; km < 2; ++km)
#pragma unroll
                for (int ln = 0; ln < 6; ++ln)
                    acc[km][ln] = __builtin_amdgcn_mfma_f32_16x16x32_bf16(a[km], b[ln], acc[km][ln], 0, 0, 0);
        }
        __syncthreads();
    }
#pragma unroll
    for (int km = 0; km < 2; ++km)
#pragma unroll
        for (int ln = 0; ln < 6; ++ln)
#pragma unroll
            for (int r = 0; r < 4; ++r) {
                int row = bm * 96 + wm * 32 + km * 16 + hi * 4 + r;
                int col = bn * 192 + wn * 96 + ln * 16 + l15;
                float x = acc[km][ln][r] + b1[col];
                float g = 0.5f * x * (1.f + erff(x * 0.70710678118654752f));
                Hout[(size_t)row * H1 + col] = f2bf(g);
            }
}

// ---------------- GEMM2: (24576 x 384) @ w2t^T (256 x 384), BM=96 BN=128 -----
// Grid 512 = exactly 2 waves of 256 CUs. (r19-proven)
__global__ __launch_bounds__(384) void k_gemm2(const unsigned short* __restrict__ A,
                                               const unsigned short* __restrict__ Bt,
                                               const float* __restrict__ b2,
                                               float* __restrict__ outp) {
    __shared__ unsigned char As[12288];   // 96 x 128B
    __shared__ unsigned char Bs[16384];   // 128 x 128B
    int bid = blockIdx.x;                           // nwg = 512 = 8 * 64
    int swz = (bid & 7) * 64 + (bid >> 3);
    int bm = swz >> 1, bn = swz & 1;
    int tid = threadIdx.x, lane = tid & 63;
    int wid = tid >> 6;
    int wm = wid >> 1, wn = wid & 1;      // 3 x 2
    int l15 = lane & 15, hi = lane >> 4;
    f32x4 acc[2][4] = {};
    const unsigned short* Abase = A + (size_t)(bm * 96) * H1;
    const unsigned short* Bbase = Bt + (size_t)(bn * 128) * H1;
    for (int kt = 0; kt < H1 / 64; ++kt) {        // 6
#pragma unroll
        for (int q = 0; q < 2; ++q) {             // A: 96 x 8 units = 768
            int e = q * 384 + tid;
            int row = e >> 3, su = (e & 7) ^ (row & 7);
            GLOAD16(Abase + (size_t)row * H1 + kt * 64 + su * 8,
                    As + q * 6144 + wid * 1024);
        }
#pragma unroll
        for (int q = 0; q < 3; ++q) {             // B: 128 x 8 units = 1024
            if (q < 2 || tid < 256) {
                int e = q * 384 + tid;
                int row = e >> 3, su = (e & 7) ^ (row & 7);
                GLOAD16(Bbase + (size_t)row * H1 + kt * 64 + su * 8,
                        Bs + q * 6144 + wid * 1024);
            }
        }
        __syncthreads();
#pragma unroll
        for (int ks = 0; ks < 2; ++ks) {
            int colb = ks * 64 + hi * 16;
            bf16x8 a[2], b[4];
#pragma unroll
            for (int km = 0; km < 2; ++km) {
                int arow = wm * 32 + km * 16 + l15;
                a[km] = *(const bf16x8*)(As + arow * 128 + (colb ^ ((arow & 7) << 4)));
            }
#pragma unroll
            for (int ln = 0; ln < 4; ++ln) {
                int brow = wn * 64 + ln * 16 + l15;
                b[ln] = *(const bf16x8*)(Bs + brow * 128 + (colb ^ ((brow & 7) << 4)));
            }
#pragma unroll
            for (int km = 0; km < 2; ++km)
#pragma unroll
                for (int ln = 0; ln < 4; ++ln)
                    acc[km][ln] = __builtin_amdgcn_mfma_f32_16x16x32_bf16(a[km], b[ln], acc[km][ln], 0, 0, 0);
        }
        __syncthreads();
    }
#pragma unroll
    for (int km = 0; km < 2; ++km)
#pragma unroll
        for (int ln = 0; ln < 4; ++ln)
#pragma unroll
            for (int r = 0; r < 4; ++r) {
                int row = bm * 96 + wm * 32 + km * 16 + hi * 4 + r;
                int col = bn * 128 + wn * 64 + ln * 16 + l15;
                int lvl = row / (T_ * N_);
                int r2 = row - lvl * (T_ * N_);
                outp[(size_t)r2 * (4 * OUTC) + lvl * OUTC + col] = acc[km][ln][r] + b2[col];
            }
}

extern "C" void kernel_launch(void* const* d_in, const int* in_sizes, int n_in,
                              void* d_out, int out_size, void* d_ws, size_t ws_size,
                              hipStream_t stream) {
    const float* fmaps   = (const float*)d_in[0];
    const float* coords  = (const float*)d_in[1];
    const float* qcoords = (const float*)d_in[2];
    const int*   qframes = (const int*)d_in[3];
    const float* w1      = (const float*)d_in[4];
    const float* b1      = (const float*)d_in[5];
    const float* w2      = (const float*)d_in[6];
    const float* b2      = (const float*)d_in[7];
    float* outp = (float*)d_out;

    unsigned char* ws = (unsigned char*)d_ws;
    size_t off = 0;
    auto take = [&](size_t bytes) {
        unsigned char* p = ws + off;
        off += (bytes + 255) & ~(size_t)255;
        return p;
    };
    // padded pyramid buffers
    const int Hs[4] = {96, 48, 24, 12}, Wss[4] = {128, 64, 32, 16};
    unsigned short* fmraw[4];
    unsigned short* fmint[4];
    for (int l = 0; l < 4; ++l) {
        int PH = Hs[l] + 2 * PAD, PW = Wss[l] + 2 * PAD;
        fmraw[l] = (unsigned short*)take((size_t)T_ * PH * PW * D_ * 2);
        fmint[l] = fmraw[l] + ((size_t)PAD * PW + PAD) * D_;
    }
    unsigned short* tfg  = (unsigned short*)take((size_t)4 * N_ * 64 * D_ * 2);
    unsigned short* vol  = (unsigned short*)take((size_t)MTOT * K2 * 2);
    unsigned short* hbuf = (unsigned short*)take((size_t)MTOT * H1 * 2);
    unsigned short* w1t  = (unsigned short*)take((size_t)H1 * K2 * 2);
    unsigned short* w2t  = (unsigned short*)take((size_t)OUTC * H1 * 2);

    hipLaunchKernelGGL(k_padzero, dim3(256, 4), dim3(256), 0, stream,
                       (uint4*)fmraw[0], (uint4*)fmraw[1], (uint4*)fmraw[2], (uint4*)fmraw[3]);
    hipLaunchKernelGGL(k_w1t, dim3(6, 49), dim3(256), 0, stream, w1, w1t);
    hipLaunchKernelGGL(k_w2t, dim3((OUTC * H1 + 255) / 256), dim3(256), 0, stream, w2, w2t);
    hipLaunchKernelGGL(k_normalize, dim3(T_ * H_), dim3(256), 0, stream, fmaps, fmint[0]);
    hipLaunchKernelGGL(k_pool, dim3((T_ * 48 * 64 * 32 + 255) / 256), dim3(256), 0, stream,
                       fmint[0], fmint[1], 96, 128);
    hipLaunchKernelGGL(k_pool, dim3((T_ * 24 * 32 * 32 + 255) / 256), dim3(256), 0, stream,
                       fmint[1], fmint[2], 48, 64);
    hipLaunchKernelGGL(k_pool, dim3((T_ * 12 * 16 * 32 + 255) / 256), dim3(256), 0, stream,
                       fmint[2], fmint[3], 24, 32);

    hipLaunchKernelGGL(k_tf, dim3(N_, 4), dim3(256), 0, stream,
                       fmint[0], fmint[1], fmint[2], fmint[3], qcoords, qframes, tfg);
    hipLaunchKernelGGL(k_cfvol, dim3(N_, T_ / 2, 4), dim3(512), 0, stream,
                       fmint[0], fmint[1], fmint[2], fmint[3], coords, tfg, vol);
    hipLaunchKernelGGL(k_gemm1, dim3(512), dim3(384), 0, stream, vol, w1t, b1, hbuf);
    hipLaunchKernelGGL(k_gemm2, dim3(512), dim3(384), 0, stream, hbuf, w2t, b2, outp);
}